// Round 4
// baseline (940.398 us; speedup 1.0000x reference)
//
#include <hip/hip_runtime.h>
#include <math.h>

#define NVV 25000
#define NCC 12500
#define NEE 250000
#define KP 160   // padded K for all bf16 GEMM inputs (covers K=128,136,144)

typedef short bf16x8 __attribute__((ext_vector_type(8)));
typedef float f32x4 __attribute__((ext_vector_type(4)));

// ---------- helpers ----------
__device__ __forceinline__ unsigned short f2bf(float f) {  // RNE fp32->bf16
  unsigned u = __float_as_uint(f);
  u += 0x7fffu + ((u >> 16) & 1u);
  return (unsigned short)(u >> 16);
}
__device__ __forceinline__ float bf2f(unsigned short u) {
  return __uint_as_float((unsigned)u << 16);
}
__device__ __forceinline__ void gll16(const unsigned short* g, unsigned short* l) {
  __builtin_amdgcn_global_load_lds(
      (const __attribute__((address_space(1))) unsigned int*)(const void*)g,
      (__attribute__((address_space(3))) unsigned int*)(void*)l, 16, 0, 0);
}

// Stage a 64-row x 160-k bf16 strip (20KB) into LDS chunk layout [kk][row64][32].
// 5 x global_load_lds_dwordx4 per thread, contiguous 320B-per-row consumption.
__device__ __forceinline__ void stage_rows64(const unsigned short* __restrict__ X,
                                             unsigned short* As, int row0, int N,
                                             int wave, int lane) {
  #pragma unroll
  for (int j = 0; j < 5; ++j) {
    int inst = wave * 5 + j;                 // 0..19
    int L = inst * 1024 + lane * 16;         // byte offset in As
    int kk = L >> 12;                        // 4096B per chunk (64 rows x 64B)
    int r = (L >> 6) & 63;
    int ks = (L & 63) >> 1;
    int grow = row0 + r; if (grow >= N) grow = N - 1;
    gll16(X + (size_t)grow * KP + kk * 32 + ks, As + inst * 512);
  }
}

template <int MI, int NI>
__device__ __forceinline__ void zero_acc(f32x4 (&acc)[MI][NI]) {
  #pragma unroll
  for (int mi = 0; mi < MI; ++mi)
    #pragma unroll
    for (int ni = 0; ni < NI; ++ni) {
      acc[mi][ni][0] = 0.f; acc[mi][ni][1] = 0.f;
      acc[mi][ni][2] = 0.f; acc[mi][ni][3] = 0.f;
    }
}

// One K-chunk (32) of MFMA: A fragments from LDS (64-row chunks), B fragments
// straight from global (weights are a 40KB L2-hot table shared by all blocks).
template <int MI, int NI>
__device__ __forceinline__ void chunk_mfma_g(const unsigned short* As,
                                             const unsigned short* __restrict__ WT,
                                             f32x4 (&acc)[MI][NI], int kk,
                                             int wm, int wn, int fr, int fq) {
  bf16x8 av[MI], bv[NI];
  #pragma unroll
  for (int mi = 0; mi < MI; ++mi)
    av[mi] = *(const bf16x8*)&As[kk * 2048 + (wm + mi * 16 + fr) * 32 + fq * 8];
  #pragma unroll
  for (int ni = 0; ni < NI; ++ni)
    bv[ni] = *(const bf16x8*)&WT[(size_t)(wn + ni * 16 + fr) * KP + kk * 32 + fq * 8];
  #pragma unroll
  for (int mi = 0; mi < MI; ++mi)
    #pragma unroll
    for (int ni = 0; ni < NI; ++ni)
      acc[mi][ni] = __builtin_amdgcn_mfma_f32_16x16x32_bf16(av[mi], bv[ni],
                                                            acc[mi][ni], 0, 0, 0);
}

// ---------- batched bf16 MFMA GEMM: out[N,128] = X[N,160] @ WT^T ----------
struct GJob {
  const unsigned short* X; const unsigned short* WT;
  const float* bias; const float* addf;
  float* outf; unsigned short* outb;
  int outb_stride, pad_flag, N, relu_flag;
};
struct GBatch { GJob j[4]; int start[4]; int njobs; };

__global__ __launch_bounds__(256, 8) void gemm_batch(GBatch B) {
  int job = 0;
  #pragma unroll
  for (int t = 1; t < 4; ++t)
    if (t < B.njobs && (int)blockIdx.x >= B.start[t]) job = t;
  GJob g = B.j[job];
  __shared__ unsigned short As[5 * 64 * 32];   // 20 KB
  const int tid = threadIdx.x;
  const int lane = tid & 63, wave = tid >> 6;
  const int row0 = (blockIdx.x - B.start[job]) * 64;
  const int wm = (wave & 1) * 32, wn = (wave >> 1) * 64;
  const int fr = lane & 15, fq = lane >> 4;

  stage_rows64(g.X, As, row0, g.N, wave, lane);
  f32x4 acc[2][4];
  zero_acc<2, 4>(acc);
  __syncthreads();
  #pragma unroll
  for (int kk = 0; kk < 5; ++kk) chunk_mfma_g<2, 4>(As, g.WT, acc, kk, wm, wn, fr, fq);

  #pragma unroll
  for (int mi = 0; mi < 2; ++mi) {
    #pragma unroll
    for (int ni = 0; ni < 4; ++ni) {
      int gcol = wn + ni * 16 + fr;
      float bvv = g.bias ? g.bias[gcol] : 0.0f;
      #pragma unroll
      for (int r = 0; r < 4; ++r) {
        int grow = row0 + wm + mi * 16 + fq * 4 + r;
        if (grow < g.N) {
          float o = acc[mi][ni][r] + bvv;
          if (g.addf) o += g.addf[(size_t)grow * 128 + gcol];
          if (g.relu_flag) o = fmaxf(o, 0.f);
          if (g.outf) g.outf[(size_t)grow * 128 + gcol] = o;
          if (g.outb) g.outb[(size_t)grow * g.outb_stride + gcol] = f2bf(o);
        }
      }
    }
    if (g.outb && g.pad_flag && wn == 0) {
      #pragma unroll
      for (int r = 0; r < 4; ++r) {
        int grow = row0 + wm + mi * 16 + fq * 4 + r;
        if (grow < g.N)
          for (int pc = 128 + fr; pc < g.outb_stride; pc += 16)
            g.outb[(size_t)grow * g.outb_stride + pc] = 0;
      }
    }
  }
}

// ---------- NI=5 GEMM: t[N,160] = X[N,160(K=128)] @ W'[160,K], bf16 out ----
__global__ __launch_bounds__(256, 4) void gemm_t(
    const unsigned short* __restrict__ X, const unsigned short* __restrict__ WT,
    unsigned short* __restrict__ outb, int N) {
  __shared__ unsigned short As[5 * 64 * 32];
  const int tid = threadIdx.x;
  const int lane = tid & 63, wave = tid >> 6;
  const int row0 = blockIdx.x * 64;
  const int wm = (wave & 1) * 32, wn = (wave >> 1) * 80;
  const int fr = lane & 15, fq = lane >> 4;

  stage_rows64(X, As, row0, N, wave, lane);
  f32x4 acc[2][5];
  zero_acc<2, 5>(acc);
  __syncthreads();
  #pragma unroll
  for (int kk = 0; kk < 5; ++kk) chunk_mfma_g<2, 5>(As, WT, acc, kk, wm, wn, fr, fq);

  #pragma unroll
  for (int mi = 0; mi < 2; ++mi)
    #pragma unroll
    for (int ni = 0; ni < 5; ++ni) {
      int gcol = wn + ni * 16 + fr;
      #pragma unroll
      for (int r = 0; r < 4; ++r) {
        int grow = row0 + wm + mi * 16 + fq * 4 + r;
        if (grow < N) outb[(size_t)grow * KP + gcol] = f2bf(acc[mi][ni][r]);
      }
    }
}

// ---------- chained GEMM: X@W1(+b1,+gather,relu) -> @W2 -> [@W3] ----------
// 64-row tile; stage-k output feeds stage-k+1 through LDS (bf16, chunk layout).
// LDS 20KB + VGPR<=64 -> 8 blocks/CU.
__global__ __launch_bounds__(256, 8) void gemm_chain(
    const unsigned short* __restrict__ X,
    const unsigned short* __restrict__ W1, const float* __restrict__ b1,
    const unsigned short* __restrict__ gA, const unsigned short* __restrict__ gB,
    const int* __restrict__ giA, const int* __restrict__ giB,
    const unsigned short* __restrict__ W2, const float* __restrict__ b2,
    const unsigned short* __restrict__ W3, const float* __restrict__ b3,
    float* __restrict__ outf, unsigned short* __restrict__ outw,
    int N, int relu_last) {
  __shared__ unsigned short As[5 * 64 * 32];   // 20 KB, reused for T2
  const int tid = threadIdx.x;
  const int lane = tid & 63, wave = tid >> 6;
  const int row0 = blockIdx.x * 64;
  const int wm = (wave & 1) * 32, wn = (wave >> 1) * 64;
  const int fr = lane & 15, fq = lane >> 4;

  // ---- stage 1 ----
  stage_rows64(X, As, row0, N, wave, lane);
  f32x4 acc[2][4];
  zero_acc<2, 4>(acc);
  __syncthreads();
  #pragma unroll
  for (int kk = 0; kk < 5; ++kk) chunk_mfma_g<2, 4>(As, W1, acc, kk, wm, wn, fr, fq);

  // ---- epilogue 1 -> T2 (reuse As) ----
  __syncthreads();                       // all stage-1 LDS reads finished
  #pragma unroll
  for (int mi = 0; mi < 2; ++mi) {
    #pragma unroll
    for (int ni = 0; ni < 4; ++ni) {
      int col = wn + ni * 16 + fr;
      float bvv = b1 ? b1[col] : 0.0f;
      #pragma unroll
      for (int r = 0; r < 4; ++r) {
        int row = wm + mi * 16 + fq * 4 + r;
        int grow = row0 + row;
        int gi = (grow < N) ? grow : (N - 1);
        float o = acc[mi][ni][r] + bvv;
        if (gA) o += bf2f(gA[(size_t)giA[gi] * 128 + col]) +
                     bf2f(gB[(size_t)giB[gi] * 128 + col]);
        o = fmaxf(o, 0.f);
        As[(col >> 5) * 2048 + row * 32 + (col & 31)] = f2bf(o);
      }
    }
  }
  zero_acc<2, 4>(acc);
  __syncthreads();                       // T2 visible

  // ---- stage 2 ----
  #pragma unroll
  for (int kk = 0; kk < 4; ++kk) chunk_mfma_g<2, 4>(As, W2, acc, kk, wm, wn, fr, fq);

  if (W3) {
    __syncthreads();
    #pragma unroll
    for (int mi = 0; mi < 2; ++mi) {
      #pragma unroll
      for (int ni = 0; ni < 4; ++ni) {
        int col = wn + ni * 16 + fr;
        float bvv = b2 ? b2[col] : 0.0f;
        #pragma unroll
        for (int r = 0; r < 4; ++r) {
          int row = wm + mi * 16 + fq * 4 + r;
          float o = fmaxf(acc[mi][ni][r] + bvv, 0.f);
          As[(col >> 5) * 2048 + row * 32 + (col & 31)] = f2bf(o);
        }
      }
    }
    zero_acc<2, 4>(acc);
    __syncthreads();
    #pragma unroll
    for (int kk = 0; kk < 4; ++kk) chunk_mfma_g<2, 4>(As, W3, acc, kk, wm, wn, fr, fq);
    #pragma unroll
    for (int mi = 0; mi < 2; ++mi)
      #pragma unroll
      for (int ni = 0; ni < 4; ++ni) {
        int gcol = wn + ni * 16 + fr;
        float bvv = b3 ? b3[gcol] : 0.0f;
        #pragma unroll
        for (int r = 0; r < 4; ++r) {
          int grow = row0 + wm + mi * 16 + fq * 4 + r;
          if (grow < N) {
            float o = acc[mi][ni][r] + bvv;
            if (relu_last) o = fmaxf(o, 0.f);
            if (outw) outw[(size_t)grow * 128 + gcol] = f2bf(o);
            else      __builtin_nontemporal_store(o, &outf[(size_t)grow * 128 + gcol]);
          }
        }
      }
  } else {
    #pragma unroll
    for (int mi = 0; mi < 2; ++mi)
      #pragma unroll
      for (int ni = 0; ni < 4; ++ni) {
        int gcol = wn + ni * 16 + fr;
        float bvv = b2 ? b2[gcol] : 0.0f;
        #pragma unroll
        for (int r = 0; r < 4; ++r) {
          int grow = row0 + wm + mi * 16 + fq * 4 + r;
          if (grow < N) {
            float o = acc[mi][ni][r] + bvv;
            if (relu_last) o = fmaxf(o, 0.f);
            if (outw) outw[(size_t)grow * 128 + gcol] = f2bf(o);
            else      __builtin_nontemporal_store(o, &outf[(size_t)grow * 128 + gcol]);
          }
        }
      }
  }
}

// ---------- build bf16 combined features ----------
__global__ void build_node_bf(const float* __restrict__ learned, const float* __restrict__ lp,
                              unsigned short* __restrict__ out, int N) {
  int idx = blockIdx.x * blockDim.x + threadIdx.x;
  if (idx >= N * 40) return;
  int row = idx / 40, c4 = idx - row * 40;
  int c = c4 * 4;
  ushort4 o;
  if (c4 < 32) {
    const float* p = learned + (size_t)row * 128 + c;
    o.x = f2bf(p[0]); o.y = f2bf(p[1]); o.z = f2bf(p[2]); o.w = f2bf(p[3]);
  } else if (c4 < 36) {
    const float* p = lp + (size_t)row * 16 + (c - 128);
    o.x = f2bf(p[0]); o.y = f2bf(p[1]); o.z = f2bf(p[2]); o.w = f2bf(p[3]);
  } else { o.x = o.y = o.z = o.w = 0; }
  *(ushort4*)&out[(size_t)row * KP + c] = o;
}

__global__ void build_edge_bf(const float* __restrict__ el, const float* __restrict__ lo,
                              const float* __restrict__ hi, const float* __restrict__ dm,
                              const float* __restrict__ wo, unsigned short* __restrict__ out) {
  int idx = blockIdx.x * blockDim.x + threadIdx.x;
  if (idx >= NEE * 40) return;
  int row = idx / 40, c4 = idx - row * 40;
  int c = c4 * 4;
  ushort4 o;
  if (c4 < 32) {
    const float* p = el + (size_t)row * 128 + c;
    o.x = f2bf(p[0]); o.y = f2bf(p[1]); o.z = f2bf(p[2]); o.w = f2bf(p[3]);
  } else if (c4 == 32) {
    o.x = f2bf(lo[row]); o.y = f2bf(hi[row]); o.z = f2bf(dm[row]);
    o.w = f2bf(wo[(size_t)row * 5 + 0]);
  } else if (c4 == 33) {
    const float* p = wo + (size_t)row * 5;
    o.x = f2bf(p[1]); o.y = f2bf(p[2]); o.z = f2bf(p[3]); o.w = f2bf(p[4]);
  } else { o.x = o.y = o.z = o.w = 0; }
  *(ushort4*)&out[(size_t)row * KP + c] = o;
}

// ---------- weight transpose/copy + convert ----------
// TR=1: O[col][k] = W[k,col] (col<128, k<K)     — GEMM weight layout
// TR=0: O[i][o]   = W[i,o]   (i<136, o<K=128)   — straight copy (We for t-GEMM)
struct WJobs {
  const float* W[20];
  unsigned short* O[20];
  int K[20];
  int TR[20];
};
__global__ void convert_weights(WJobs j) {
  int b = blockIdx.x;
  int job = b / 100;
  int i = (b - job * 100) * 256 + threadIdx.x;   // 0 .. 160*KP
  int col = i / KP;
  int k = i - col * KP;
  float v = 0.f;
  if (j.TR[job]) { if (col < 128 && k < j.K[job]) v = j.W[job][(size_t)k * 128 + col]; }
  else           { if (col < 136 && k < j.K[job]) v = j.W[job][(size_t)col * 128 + k]; }
  j.O[job][(size_t)col * KP + k] = f2bf(v);
}

// ---------- CSR construction ----------
__global__ void zero2(int* __restrict__ a, int na, int* __restrict__ b, int nb) {
  int i = blockIdx.x * blockDim.x + threadIdx.x;
  if (i < na) a[i] = 0;
  if (i < nb) b[i] = 0;
}
__global__ void hist2(const int* __restrict__ dc, int* __restrict__ cc,
                      const int* __restrict__ dv, int* __restrict__ cv, int nE) {
  int e = blockIdx.x * blockDim.x + threadIdx.x;
  if (e >= nE) return;
  atomicAdd(&cc[dc[e]], 1);
  atomicAdd(&cv[dv[e]], 1);
}
// single block 256 threads
__global__ void csr_scan(const int* __restrict__ counts, int* __restrict__ offsets,
                         int* __restrict__ cursor, int n) {
  __shared__ int part[256];
  int tid = threadIdx.x;
  int chunk = (n + 255) / 256;
  int lo = tid * chunk, hi = min(n, lo + chunk);
  int s = 0;
  for (int i = lo; i < hi; ++i) s += counts[i];
  part[tid] = s;
  __syncthreads();
  if (tid == 0) {
    int run = 0;
    for (int i = 0; i < 256; ++i) { int t = part[i]; part[i] = run; run += t; }
    offsets[n] = run;
  }
  __syncthreads();
  int base = part[tid];
  for (int i = lo; i < hi; ++i) { offsets[i] = base; cursor[i] = base; base += counts[i]; }
}
__global__ void csr_scatter(const int* __restrict__ dst, const int* __restrict__ src,
                            int* __restrict__ cursor, int2* __restrict__ ces, int nE) {
  int e = blockIdx.x * blockDim.x + threadIdx.x;
  if (e >= nE) return;
  int pos = atomicAdd(&cursor[dst[e]], 1);
  ces[pos] = make_int2(e, src[e]);
}

// ---------- fused flash-style segment attention: one wave per dst ----------
// ee eliminated algebraically:  q·ee = t·e with t = We@q (bf16, [Nd,160]);
// Σ a·ee = (Σ a·e)@We  -> accumulate 136-dim weighted edge sum, transform later.
// k/v are bf16 [Ns,128]. 4-edge unrolled loop for load-level parallelism.
struct AttSt { float m, l, ax, ay, axe, aye, axe2, aye2; };
__device__ __forceinline__ void att_upd(AttSt& s, float alpha, unsigned vu,
                                        float e0, float e1, float e2, float e3) {
  float mn = fmaxf(s.m, alpha);
  float scale = __expf(s.m - mn);
  float w = __expf(alpha - mn);
  s.ax = s.ax * scale + __uint_as_float(vu << 16) * w;
  s.ay = s.ay * scale + __uint_as_float(vu & 0xffff0000u) * w;
  s.axe = s.axe * scale + e0 * w;   s.aye = s.aye * scale + e1 * w;
  s.axe2 = s.axe2 * scale + e2 * w; s.aye2 = s.aye2 * scale + e3 * w;
  s.l = s.l * scale + w; s.m = mn;
}

__global__ void fused_attn(
    const float* __restrict__ qbuf, const unsigned short* __restrict__ kbuf,
    const unsigned short* __restrict__ vbuf, const unsigned short* __restrict__ tbuf,
    const unsigned short* __restrict__ ecomb,
    const int* __restrict__ offsets, const int2* __restrict__ ces,
    float* __restrict__ accVS, unsigned short* __restrict__ accE, int Nd) {
  int d = blockIdx.x * 4 + (threadIdx.x >> 6);
  if (d >= Nd) return;
  int lane = threadIdx.x & 63;
  int c = lane * 2;
  bool tl = (lane < 16);
  int c2 = 128 + c;                     // tail cols for lanes 0..15
  float2 qv = *(const float2*)&qbuf[(size_t)d * 128 + c];
  unsigned tu = *(const unsigned*)&tbuf[(size_t)d * KP + c];
  float tx = __uint_as_float(tu << 16);
  float ty = __uint_as_float(tu & 0xffff0000u);
  float tx2 = 0.f, ty2 = 0.f;
  if (tl) {
    unsigned tu2 = *(const unsigned*)&tbuf[(size_t)d * KP + c2];
    tx2 = __uint_as_float(tu2 << 16);
    ty2 = __uint_as_float(tu2 & 0xffff0000u);
  }
  int beg = offsets[d], end = offsets[d + 1];
  AttSt st{-INFINITY, 0.f, 0.f, 0.f, 0.f, 0.f, 0.f, 0.f};
  const float SC = 0.08838834764831845f;  // 1/sqrt(128)
  int i = beg;
  for (; i + 3 < end; i += 4) {
    int2 pr[4];
    pr[0] = ces[i]; pr[1] = ces[i + 1]; pr[2] = ces[i + 2]; pr[3] = ces[i + 3];
    unsigned eu[4], ku[4], vu[4];
    float e0[4], e1[4], e2[4], e3[4], p[4];
    #pragma unroll
    for (int u = 0; u < 4; ++u) {
      eu[u] = *(const unsigned*)&ecomb[(size_t)pr[u].x * KP + c];
      ku[u] = *(const unsigned*)&kbuf[(size_t)pr[u].y * 128 + c];
      vu[u] = *(const unsigned*)&vbuf[(size_t)pr[u].y * 128 + c];
    }
    #pragma unroll
    for (int u = 0; u < 4; ++u) {
      e0[u] = __uint_as_float(eu[u] << 16);
      e1[u] = __uint_as_float(eu[u] & 0xffff0000u);
      e2[u] = 0.f; e3[u] = 0.f;
    }
    if (tl) {
      #pragma unroll
      for (int u = 0; u < 4; ++u) {
        unsigned x = *(const unsigned*)&ecomb[(size_t)pr[u].x * KP + c2];
        e2[u] = __uint_as_float(x << 16);
        e3[u] = __uint_as_float(x & 0xffff0000u);
      }
    }
    #pragma unroll
    for (int u = 0; u < 4; ++u)
      p[u] = qv.x * __uint_as_float(ku[u] << 16) + qv.y * __uint_as_float(ku[u] & 0xffff0000u)
           + tx * e0[u] + ty * e1[u] + tx2 * e2[u] + ty2 * e3[u];
    #pragma unroll
    for (int off = 1; off < 64; off <<= 1) {
      p[0] += __shfl_xor(p[0], off, 64);
      p[1] += __shfl_xor(p[1], off, 64);
      p[2] += __shfl_xor(p[2], off, 64);
      p[3] += __shfl_xor(p[3], off, 64);
    }
    #pragma unroll
    for (int u = 0; u < 4; ++u)
      att_upd(st, p[u] * SC, vu[u], e0[u], e1[u], e2[u], e3[u]);
  }
  for (; i < end; ++i) {
    int2 pr = ces[i];
    unsigned eu = *(const unsigned*)&ecomb[(size_t)pr.x * KP + c];
    float e0 = __uint_as_float(eu << 16);
    float e1 = __uint_as_float(eu & 0xffff0000u);
    float e2 = 0.f, e3 = 0.f;
    if (tl) {
      unsigned x = *(const unsigned*)&ecomb[(size_t)pr.x * KP + c2];
      e2 = __uint_as_float(x << 16);
      e3 = __uint_as_float(x & 0xffff0000u);
    }
    unsigned ku = *(const unsigned*)&kbuf[(size_t)pr.y * 128 + c];
    unsigned vu = *(const unsigned*)&vbuf[(size_t)pr.y * 128 + c];
    float p = qv.x * __uint_as_float(ku << 16) + qv.y * __uint_as_float(ku & 0xffff0000u)
            + tx * e0 + ty * e1 + tx2 * e2 + ty2 * e3;
    #pragma unroll
    for (int off = 1; off < 64; off <<= 1) p += __shfl_xor(p, off, 64);
    att_upd(st, p * SC, vu, e0, e1, e2, e3);
  }
  int deg = end - beg;
  float inv = (deg > 0) ? 1.0f / (st.l * (float)deg) : 0.0f;
  float2 sk = *(const float2*)&accVS[(size_t)d * 128 + c];
  *(float2*)&accVS[(size_t)d * 128 + c] =
      make_float2(st.ax * inv + sk.x, st.ay * inv + sk.y);
  ushort2 oe; oe.x = f2bf(st.axe * inv); oe.y = f2bf(st.aye * inv);
  *(ushort2*)&accE[(size_t)d * KP + c] = oe;
  if (tl) {
    ushort2 oe2; oe2.x = f2bf(st.axe2 * inv); oe2.y = f2bf(st.aye2 * inv);
    *(ushort2*)&accE[(size_t)d * KP + c2] = oe2;
  }
}

extern "C" void kernel_launch(void* const* d_in, const int* in_sizes, int n_in,
                              void* d_out, int out_size, void* d_ws, size_t ws_size,
                              hipStream_t stream) {
  const float* var_learned = (const float*)d_in[0];
  const float* var_lp      = (const float*)d_in[1];
  const float* con_learned = (const float*)d_in[2];
  const float* con_lp      = (const float*)d_in[3];
  const float* edge_learned= (const float*)d_in[4];
  const float* lo          = (const float*)d_in[5];
  const float* hi          = (const float*)d_in[6];
  const float* dm          = (const float*)d_in[7];
  const float* wo          = (const float*)d_in[8];
  const float* cu_Wq = (const float*)d_in[9],  *cu_bq = (const float*)d_in[10];
  const float* cu_Wk = (const float*)d_in[11], *cu_bk = (const float*)d_in[12];
  const float* cu_Wv = (const float*)d_in[13], *cu_bv = (const float*)d_in[14];
  const float* cu_We = (const float*)d_in[15];
  const float* cu_Ws = (const float*)d_in[16], *cu_bs = (const float*)d_in[17];
  const float* vu_Wq = (const float*)d_in[18], *vu_bq = (const float*)d_in[19];
  const float* vu_Wk = (const float*)d_in[20], *vu_bk = (const float*)d_in[21];
  const float* vu_Wv = (const float*)d_in[22], *vu_bv = (const float*)d_in[23];
  const float* vu_We = (const float*)d_in[24];
  const float* vu_Ws = (const float*)d_in[25], *vu_bs = (const float*)d_in[26];
  const float* eu_vW1 = (const float*)d_in[27], *eu_vb1 = (const float*)d_in[28];
  const float* eu_vW2 = (const float*)d_in[29], *eu_vb2 = (const float*)d_in[30];
  const float* eu_cW1 = (const float*)d_in[31], *eu_cb1 = (const float*)d_in[32];
  const float* eu_cW2 = (const float*)d_in[33], *eu_cb2 = (const float*)d_in[34];
  const float* eu_eW1 = (const float*)d_in[35], *eu_eb1 = (const float*)d_in[36];
  const float* eu_eW2 = (const float*)d_in[37], *eu_eb2 = (const float*)d_in[38];
  const int* eiv = (const int*)d_in[39];
  const int* eic = (const int*)d_in[40];

  float* out_var  = (float*)d_out;
  float* out_con  = out_var + (size_t)NVV * 128;
  float* out_edge = out_con + (size_t)NCC * 128;

  // ---- workspace arena ----
  char* w = (char*)d_ws;
  auto alloc = [&](size_t bytes) { char* p = w; w += (bytes + 255) & ~(size_t)255; return p; };
  unsigned short* edge_comb_bf = (unsigned short*)alloc((size_t)NEE * KP * 2);  // 80MB
  unsigned short* var_comb_bf = (unsigned short*)alloc((size_t)NVV * KP * 2);
  unsigned short* con_comb_bf = (unsigned short*)alloc((size_t)NCC * KP * 2);
  unsigned short* q_bf    = (unsigned short*)alloc((size_t)NVV * KP * 2);
  unsigned short* t_bf    = (unsigned short*)alloc((size_t)NVV * KP * 2);
  unsigned short* accE_bf = (unsigned short*)alloc((size_t)NVV * KP * 2);
  unsigned short* kv_bf   = (unsigned short*)alloc((size_t)NVV * 128 * 2);
  unsigned short* vv_bf   = (unsigned short*)alloc((size_t)NVV * 128 * 2);
  unsigned short* vc_bf   = (unsigned short*)alloc((size_t)NVV * 128 * 2);
  unsigned short* cc_bf   = (unsigned short*)alloc((size_t)NCC * 128 * 2);
  float* bufV1 = (float*)alloc((size_t)NVV * 128 * 4);
  float* bufV2 = (float*)alloc((size_t)NVV * 128 * 4);
  float* bufC1 = (float*)alloc((size_t)NCC * 128 * 4);
  float* bufC2 = (float*)alloc((size_t)NCC * 128 * 4);
  unsigned short* WTbase = (unsigned short*)alloc((size_t)20 * 160 * KP * 2);
  int* countsC = (int*)alloc((size_t)NCC * 4);
  int* countsV = (int*)alloc((size_t)NVV * 4);
  int* offC = (int*)alloc((size_t)(NCC + 1) * 4);
  int* curC = (int*)alloc((size_t)NCC * 4);
  int* offV = (int*)alloc((size_t)(NVV + 1) * 4);
  int* curV = (int*)alloc((size_t)NVV * 4);
  int2* cesA = (int2*)alloc((size_t)NEE * 8);  // conv A (dst=con): {edge, src}
  int2* cesB = (int2*)alloc((size_t)NEE * 8);  // conv B (dst=var)
  (void)ws_size; (void)in_sizes; (void)n_in; (void)out_size;

  unsigned short* WT[20];
  for (int i = 0; i < 20; ++i) WT[i] = WTbase + (size_t)i * 160 * KP;
  WJobs jobs;
  const float* Wsrc[20] = {cu_Wq, cu_Wk, cu_Wv, cu_We, cu_Ws,
                           vu_Wq, vu_Wk, vu_Wv, vu_We, vu_Ws,
                           eu_vW1, eu_vW2, eu_cW1, eu_cW2,
                           eu_eW1, eu_eW1 + 136 * 128, eu_eW1 + 264 * 128, eu_eW2,
                           cu_We, vu_We};
  const int Ksrc[20] = {144, 144, 144, 136, 144, 144, 144, 144, 136, 144,
                        144, 128, 144, 128, 136, 128, 128, 128, 128, 128};
  const int Tsrc[20] = {1,1,1,1,1, 1,1,1,1,1, 1,1,1,1, 1,1,1,1, 0,0};
  for (int i = 0; i < 20; ++i) {
    jobs.W[i] = Wsrc[i]; jobs.O[i] = WT[i]; jobs.K[i] = Ksrc[i]; jobs.TR[i] = Tsrc[i];
  }

  const int T = 256;
  const int NBC = (NCC + 63) / 64;   // 196
  const int NBV = (NVV + 63) / 64;   // 391
  const int NBE = (NEE + 63) / 64;   // 3907

  // ---- pre-passes ----
  build_node_bf<<<(NVV * 40 + T - 1) / T, T, 0, stream>>>(var_learned, var_lp, var_comb_bf, NVV);
  build_node_bf<<<(NCC * 40 + T - 1) / T, T, 0, stream>>>(con_learned, con_lp, con_comb_bf, NCC);
  build_edge_bf<<<(NEE * 40 + T - 1) / T, T, 0, stream>>>(edge_learned, lo, hi, dm, wo, edge_comb_bf);
  convert_weights<<<20 * 100, T, 0, stream>>>(jobs);

  // ---- CSR builds ----
  zero2<<<(NVV + T - 1) / T, T, 0, stream>>>(countsC, NCC, countsV, NVV);
  hist2<<<(NEE + T - 1) / T, T, 0, stream>>>(eic, countsC, eiv, countsV, NEE);
  csr_scan<<<1, 256, 0, stream>>>(countsC, offC, curC, NCC);
  csr_scan<<<1, 256, 0, stream>>>(countsV, offV, curV, NVV);
  csr_scatter<<<(NEE + T - 1) / T, T, 0, stream>>>(eic, eiv, curC, cesA, NEE);
  csr_scatter<<<(NEE + T - 1) / T, T, 0, stream>>>(eiv, eic, curV, cesB, NEE);

  // ================= Stage A: con update (src=var, dst=con) =================
  {
    GBatch b{};
    b.j[0] = {con_comb_bf, WT[0], cu_bq, nullptr, bufC1, q_bf, KP, 1, NCC, 0};   // q_c
    b.j[1] = {con_comb_bf, WT[4], cu_bs, nullptr, bufC2, nullptr, 0, 0, NCC, 0}; // skip_c
    b.j[2] = {var_comb_bf, WT[1], cu_bk, nullptr, nullptr, kv_bf, 128, 0, NVV, 0}; // k_v
    b.j[3] = {var_comb_bf, WT[2], cu_bv, nullptr, nullptr, vv_bf, 128, 0, NVV, 0}; // v_v
    b.start[0] = 0; b.start[1] = NBC; b.start[2] = 2 * NBC; b.start[3] = 2 * NBC + NBV;
    b.njobs = 4;
    gemm_batch<<<2 * NBC + 2 * NBV, 256, 0, stream>>>(b);
  }
  gemm_t<<<NBC, 256, 0, stream>>>(q_bf, WT[18], t_bf, NCC);   // t_c = We @ q_c
  fused_attn<<<(NCC + 3) / 4, 256, 0, stream>>>(bufC1, kv_bf, vv_bf, t_bf, edge_comb_bf,
                                                offC, cesA, bufC2, accE_bf, NCC);
  {
    GBatch b{};
    b.j[0] = {accE_bf, WT[3], nullptr, bufC2, out_con, con_comb_bf, KP, 0, NCC, 1};
    b.start[0] = 0; b.njobs = 1;
    gemm_batch<<<NBC, 256, 0, stream>>>(b);    // con_new = relu(accE@We + accVS)
  }

  // ================= Stage B: var update (src=new con, dst=var) =================
  {
    GBatch b{};
    b.j[0] = {var_comb_bf, WT[5], vu_bq, nullptr, bufV1, q_bf, KP, 1, NVV, 0};   // q_v
    b.j[1] = {var_comb_bf, WT[9], vu_bs, nullptr, bufV2, nullptr, 0, 0, NVV, 0}; // skip_v
    b.j[2] = {con_comb_bf, WT[6], vu_bk, nullptr, nullptr, kv_bf, 128, 0, NCC, 0}; // k_c
    b.j[3] = {con_comb_bf, WT[7], vu_bv, nullptr, nullptr, vv_bf, 128, 0, NCC, 0}; // v_c
    b.start[0] = 0; b.start[1] = NBV; b.start[2] = 2 * NBV; b.start[3] = 2 * NBV + NBC;
    b.njobs = 4;
    gemm_batch<<<2 * NBV + 2 * NBC, 256, 0, stream>>>(b);
  }
  gemm_t<<<NBV, 256, 0, stream>>>(q_bf, WT[19], t_bf, NVV);   // t_v = We @ q_v
  fused_attn<<<(NVV + 3) / 4, 256, 0, stream>>>(bufV1, kv_bf, vv_bf, t_bf, edge_comb_bf,
                                                offV, cesB, bufV2, accE_bf, NVV);
  {
    GBatch b{};
    b.j[0] = {accE_bf, WT[8], nullptr, bufV2, out_var, var_comb_bf, KP, 0, NVV, 1};
    b.start[0] = 0; b.njobs = 1;
    gemm_batch<<<NBV, 256, 0, stream>>>(b);    // var_new = relu(accE@We + accVS)
  }

  // ================= Edge stage (fully chained) =================
  gemm_chain<<<NBV, 256, 0, stream>>>(
      var_comb_bf, WT[10], eu_vb1, nullptr, nullptr, nullptr, nullptr,
      WT[11], eu_vb2, WT[15], nullptr, nullptr, vc_bf, NVV, 0);   // vcW (bf16)
  gemm_chain<<<NBC, 256, 0, stream>>>(
      con_comb_bf, WT[12], eu_cb1, nullptr, nullptr, nullptr, nullptr,
      WT[13], eu_cb2, WT[16], nullptr, nullptr, cc_bf, NCC, 0);   // ccW (bf16)
  gemm_chain<<<NBE, 256, 0, stream>>>(
      edge_comb_bf, WT[14], eu_eb1, vc_bf, cc_bf, eiv, eic,
      WT[17], eu_eb2, nullptr, nullptr, out_edge, nullptr, NEE, 1);  // edge_new
}

// Round 5
// 831.711 us; speedup vs baseline: 1.1307x; 1.1307x over previous
//
#include <hip/hip_runtime.h>
#include <math.h>

#define NVV 25000
#define NCC 12500
#define NEE 250000
#define KP 160   // padded K for all bf16 GEMM inputs (covers K=128,136,144)

typedef short bf16x8 __attribute__((ext_vector_type(8)));
typedef float f32x4 __attribute__((ext_vector_type(4)));

// ---------- helpers ----------
__device__ __forceinline__ unsigned short f2bf(float f) {  // RNE fp32->bf16
  unsigned u = __float_as_uint(f);
  u += 0x7fffu + ((u >> 16) & 1u);
  return (unsigned short)(u >> 16);
}
__device__ __forceinline__ float bf2f(unsigned short u) {
  return __uint_as_float((unsigned)u << 16);
}
__device__ __forceinline__ void gll16(const unsigned short* g, unsigned short* l) {
  __builtin_amdgcn_global_load_lds(
      (const __attribute__((address_space(1))) unsigned int*)(const void*)g,
      (__attribute__((address_space(3))) unsigned int*)(void*)l, 16, 0, 0);
}

// Stage a 64-row x 160-k bf16 strip (20KB) into LDS chunk layout [kk][row64][32].
// 5 x global_load_lds_dwordx4 per thread, contiguous 320B-per-row consumption.
__device__ __forceinline__ void stage_rows64(const unsigned short* __restrict__ X,
                                             unsigned short* As, int row0, int N,
                                             int wave, int lane) {
  #pragma unroll
  for (int j = 0; j < 5; ++j) {
    int inst = wave * 5 + j;                 // 0..19
    int L = inst * 1024 + lane * 16;         // byte offset in As
    int kk = L >> 12;                        // 4096B per chunk (64 rows x 64B)
    int r = (L >> 6) & 63;
    int ks = (L & 63) >> 1;
    int grow = row0 + r; if (grow >= N) grow = N - 1;
    gll16(X + (size_t)grow * KP + kk * 32 + ks, As + inst * 512);
  }
}

template <int MI, int NI>
__device__ __forceinline__ void zero_acc(f32x4 (&acc)[MI][NI]) {
  #pragma unroll
  for (int mi = 0; mi < MI; ++mi)
    #pragma unroll
    for (int ni = 0; ni < NI; ++ni) {
      acc[mi][ni][0] = 0.f; acc[mi][ni][1] = 0.f;
      acc[mi][ni][2] = 0.f; acc[mi][ni][3] = 0.f;
    }
}

// One K-chunk (32) of MFMA: A fragments from LDS (64-row chunks), B fragments
// straight from global (weights are a 40KB L2-hot table shared by all blocks).
template <int MI, int NI>
__device__ __forceinline__ void chunk_mfma_g(const unsigned short* As,
                                             const unsigned short* __restrict__ WT,
                                             f32x4 (&acc)[MI][NI], int kk,
                                             int wm, int wn, int fr, int fq) {
  bf16x8 av[MI], bv[NI];
  #pragma unroll
  for (int mi = 0; mi < MI; ++mi)
    av[mi] = *(const bf16x8*)&As[kk * 2048 + (wm + mi * 16 + fr) * 32 + fq * 8];
  #pragma unroll
  for (int ni = 0; ni < NI; ++ni)
    bv[ni] = *(const bf16x8*)&WT[(size_t)(wn + ni * 16 + fr) * KP + kk * 32 + fq * 8];
  #pragma unroll
  for (int mi = 0; mi < MI; ++mi)
    #pragma unroll
    for (int ni = 0; ni < NI; ++ni)
      acc[mi][ni] = __builtin_amdgcn_mfma_f32_16x16x32_bf16(av[mi], bv[ni],
                                                            acc[mi][ni], 0, 0, 0);
}

// ---------- batched bf16 MFMA GEMM: out[N,128] = X[N,160] @ WT^T ----------
struct GJob {
  const unsigned short* X; const unsigned short* WT;
  const float* bias; const float* addf;
  float* outf; unsigned short* outb;
  int outb_stride, pad_flag, N, relu_flag;
};
struct GBatch { GJob j[4]; int start[4]; int njobs; };

// combined VGPR+AGPR need ~92 -> waves/EU=5 (cap ~102) is the max spill-free.
__global__ __launch_bounds__(256, 5) void gemm_batch(GBatch B) {
  int job = 0;
  #pragma unroll
  for (int t = 1; t < 4; ++t)
    if (t < B.njobs && (int)blockIdx.x >= B.start[t]) job = t;
  GJob g = B.j[job];
  __shared__ unsigned short As[5 * 64 * 32];   // 20 KB
  const int tid = threadIdx.x;
  const int lane = tid & 63, wave = tid >> 6;
  const int row0 = (blockIdx.x - B.start[job]) * 64;
  const int wm = (wave & 1) * 32, wn = (wave >> 1) * 64;
  const int fr = lane & 15, fq = lane >> 4;

  stage_rows64(g.X, As, row0, g.N, wave, lane);
  f32x4 acc[2][4];
  zero_acc<2, 4>(acc);
  __syncthreads();
  #pragma unroll
  for (int kk = 0; kk < 5; ++kk) chunk_mfma_g<2, 4>(As, g.WT, acc, kk, wm, wn, fr, fq);

  #pragma unroll
  for (int mi = 0; mi < 2; ++mi) {
    #pragma unroll
    for (int ni = 0; ni < 4; ++ni) {
      int gcol = wn + ni * 16 + fr;
      float bvv = g.bias ? g.bias[gcol] : 0.0f;
      #pragma unroll
      for (int r = 0; r < 4; ++r) {
        int grow = row0 + wm + mi * 16 + fq * 4 + r;
        if (grow < g.N) {
          float o = acc[mi][ni][r] + bvv;
          if (g.addf) o += g.addf[(size_t)grow * 128 + gcol];
          if (g.relu_flag) o = fmaxf(o, 0.f);
          if (g.outf) g.outf[(size_t)grow * 128 + gcol] = o;
          if (g.outb) g.outb[(size_t)grow * g.outb_stride + gcol] = f2bf(o);
        }
      }
    }
    if (g.outb && g.pad_flag && wn == 0) {
      #pragma unroll
      for (int r = 0; r < 4; ++r) {
        int grow = row0 + wm + mi * 16 + fq * 4 + r;
        if (grow < g.N)
          for (int pc = 128 + fr; pc < g.outb_stride; pc += 16)
            g.outb[(size_t)grow * g.outb_stride + pc] = 0;
      }
    }
  }
}

// ---------- NI=5 GEMM: t[N,160] = X[N,160(K=128)] @ W'[160,K], bf16 out ----
__global__ __launch_bounds__(256, 4) void gemm_t(
    const unsigned short* __restrict__ X, const unsigned short* __restrict__ WT,
    unsigned short* __restrict__ outb, int N) {
  __shared__ unsigned short As[5 * 64 * 32];
  const int tid = threadIdx.x;
  const int lane = tid & 63, wave = tid >> 6;
  const int row0 = blockIdx.x * 64;
  const int wm = (wave & 1) * 32, wn = (wave >> 1) * 80;
  const int fr = lane & 15, fq = lane >> 4;

  stage_rows64(X, As, row0, N, wave, lane);
  f32x4 acc[2][5];
  zero_acc<2, 5>(acc);
  __syncthreads();
  #pragma unroll
  for (int kk = 0; kk < 5; ++kk) chunk_mfma_g<2, 5>(As, WT, acc, kk, wm, wn, fr, fq);

  #pragma unroll
  for (int mi = 0; mi < 2; ++mi)
    #pragma unroll
    for (int ni = 0; ni < 5; ++ni) {
      int gcol = wn + ni * 16 + fr;
      #pragma unroll
      for (int r = 0; r < 4; ++r) {
        int grow = row0 + wm + mi * 16 + fq * 4 + r;
        if (grow < N) outb[(size_t)grow * KP + gcol] = f2bf(acc[mi][ni][r]);
      }
    }
}

// ---------- chained GEMM: X@W1(+b1,+gather,relu) -> @W2 -> [@W3] ----------
// 64-row tile; stage-k output feeds stage-k+1 through LDS (bf16, chunk layout).
// combined VGPR+AGPR ~92 -> (256,5) is the max spill-free occupancy bound.
__global__ __launch_bounds__(256, 5) void gemm_chain(
    const unsigned short* __restrict__ X,
    const unsigned short* __restrict__ W1, const float* __restrict__ b1,
    const unsigned short* __restrict__ gA, const unsigned short* __restrict__ gB,
    const int* __restrict__ giA, const int* __restrict__ giB,
    const unsigned short* __restrict__ W2, const float* __restrict__ b2,
    const unsigned short* __restrict__ W3, const float* __restrict__ b3,
    float* __restrict__ outf, unsigned short* __restrict__ outw,
    int N, int relu_last) {
  __shared__ unsigned short As[5 * 64 * 32];   // 20 KB, reused for T2
  const int tid = threadIdx.x;
  const int lane = tid & 63, wave = tid >> 6;
  const int row0 = blockIdx.x * 64;
  const int wm = (wave & 1) * 32, wn = (wave >> 1) * 64;
  const int fr = lane & 15, fq = lane >> 4;

  // ---- stage 1 ----
  stage_rows64(X, As, row0, N, wave, lane);
  f32x4 acc[2][4];
  zero_acc<2, 4>(acc);
  __syncthreads();
  #pragma unroll
  for (int kk = 0; kk < 5; ++kk) chunk_mfma_g<2, 4>(As, W1, acc, kk, wm, wn, fr, fq);

  // ---- epilogue 1 -> T2 (reuse As) ----
  __syncthreads();                       // all stage-1 LDS reads finished
  #pragma unroll
  for (int mi = 0; mi < 2; ++mi) {
    #pragma unroll
    for (int ni = 0; ni < 4; ++ni) {
      int col = wn + ni * 16 + fr;
      float bvv = b1 ? b1[col] : 0.0f;
      #pragma unroll
      for (int r = 0; r < 4; ++r) {
        int row = wm + mi * 16 + fq * 4 + r;
        int grow = row0 + row;
        int gi = (grow < N) ? grow : (N - 1);
        float o = acc[mi][ni][r] + bvv;
        if (gA) o += bf2f(gA[(size_t)giA[gi] * 128 + col]) +
                     bf2f(gB[(size_t)giB[gi] * 128 + col]);
        o = fmaxf(o, 0.f);
        As[(col >> 5) * 2048 + row * 32 + (col & 31)] = f2bf(o);
      }
    }
  }
  zero_acc<2, 4>(acc);
  __syncthreads();                       // T2 visible

  // ---- stage 2 ----
  #pragma unroll
  for (int kk = 0; kk < 4; ++kk) chunk_mfma_g<2, 4>(As, W2, acc, kk, wm, wn, fr, fq);

  if (W3) {
    __syncthreads();
    #pragma unroll
    for (int mi = 0; mi < 2; ++mi) {
      #pragma unroll
      for (int ni = 0; ni < 4; ++ni) {
        int col = wn + ni * 16 + fr;
        float bvv = b2 ? b2[col] : 0.0f;
        #pragma unroll
        for (int r = 0; r < 4; ++r) {
          int row = wm + mi * 16 + fq * 4 + r;
          float o = fmaxf(acc[mi][ni][r] + bvv, 0.f);
          As[(col >> 5) * 2048 + row * 32 + (col & 31)] = f2bf(o);
        }
      }
    }
    zero_acc<2, 4>(acc);
    __syncthreads();
    #pragma unroll
    for (int kk = 0; kk < 4; ++kk) chunk_mfma_g<2, 4>(As, W3, acc, kk, wm, wn, fr, fq);
    #pragma unroll
    for (int mi = 0; mi < 2; ++mi)
      #pragma unroll
      for (int ni = 0; ni < 4; ++ni) {
        int gcol = wn + ni * 16 + fr;
        float bvv = b3 ? b3[gcol] : 0.0f;
        #pragma unroll
        for (int r = 0; r < 4; ++r) {
          int grow = row0 + wm + mi * 16 + fq * 4 + r;
          if (grow < N) {
            float o = acc[mi][ni][r] + bvv;
            if (relu_last) o = fmaxf(o, 0.f);
            if (outw) outw[(size_t)grow * 128 + gcol] = f2bf(o);
            else      __builtin_nontemporal_store(o, &outf[(size_t)grow * 128 + gcol]);
          }
        }
      }
  } else {
    #pragma unroll
    for (int mi = 0; mi < 2; ++mi)
      #pragma unroll
      for (int ni = 0; ni < 4; ++ni) {
        int gcol = wn + ni * 16 + fr;
        float bvv = b2 ? b2[gcol] : 0.0f;
        #pragma unroll
        for (int r = 0; r < 4; ++r) {
          int grow = row0 + wm + mi * 16 + fq * 4 + r;
          if (grow < N) {
            float o = acc[mi][ni][r] + bvv;
            if (relu_last) o = fmaxf(o, 0.f);
            if (outw) outw[(size_t)grow * 128 + gcol] = f2bf(o);
            else      __builtin_nontemporal_store(o, &outf[(size_t)grow * 128 + gcol]);
          }
        }
      }
  }
}

// ---------- build bf16 combined features ----------
__global__ void build_node_bf(const float* __restrict__ learned, const float* __restrict__ lp,
                              unsigned short* __restrict__ out, int N) {
  int idx = blockIdx.x * blockDim.x + threadIdx.x;
  if (idx >= N * 40) return;
  int row = idx / 40, c4 = idx - row * 40;
  int c = c4 * 4;
  ushort4 o;
  if (c4 < 32) {
    const float* p = learned + (size_t)row * 128 + c;
    o.x = f2bf(p[0]); o.y = f2bf(p[1]); o.z = f2bf(p[2]); o.w = f2bf(p[3]);
  } else if (c4 < 36) {
    const float* p = lp + (size_t)row * 16 + (c - 128);
    o.x = f2bf(p[0]); o.y = f2bf(p[1]); o.z = f2bf(p[2]); o.w = f2bf(p[3]);
  } else { o.x = o.y = o.z = o.w = 0; }
  *(ushort4*)&out[(size_t)row * KP + c] = o;
}

__global__ void build_edge_bf(const float* __restrict__ el, const float* __restrict__ lo,
                              const float* __restrict__ hi, const float* __restrict__ dm,
                              const float* __restrict__ wo, unsigned short* __restrict__ out) {
  int idx = blockIdx.x * blockDim.x + threadIdx.x;
  if (idx >= NEE * 40) return;
  int row = idx / 40, c4 = idx - row * 40;
  int c = c4 * 4;
  ushort4 o;
  if (c4 < 32) {
    const float* p = el + (size_t)row * 128 + c;
    o.x = f2bf(p[0]); o.y = f2bf(p[1]); o.z = f2bf(p[2]); o.w = f2bf(p[3]);
  } else if (c4 == 32) {
    o.x = f2bf(lo[row]); o.y = f2bf(hi[row]); o.z = f2bf(dm[row]);
    o.w = f2bf(wo[(size_t)row * 5 + 0]);
  } else if (c4 == 33) {
    const float* p = wo + (size_t)row * 5;
    o.x = f2bf(p[1]); o.y = f2bf(p[2]); o.z = f2bf(p[3]); o.w = f2bf(p[4]);
  } else { o.x = o.y = o.z = o.w = 0; }
  *(ushort4*)&out[(size_t)row * KP + c] = o;
}

// ---------- weight transpose/copy + convert ----------
// TR=1: O[col][k] = W[k,col] (col<128, k<K)     — GEMM weight layout
// TR=0: O[i][o]   = W[i,o]   (i<136, o<K=128)   — straight copy (We for t-GEMM)
struct WJobs {
  const float* W[20];
  unsigned short* O[20];
  int K[20];
  int TR[20];
};
__global__ void convert_weights(WJobs j) {
  int b = blockIdx.x;
  int job = b / 100;
  int i = (b - job * 100) * 256 + threadIdx.x;   // 0 .. 160*KP
  int col = i / KP;
  int k = i - col * KP;
  float v = 0.f;
  if (j.TR[job]) { if (col < 128 && k < j.K[job]) v = j.W[job][(size_t)k * 128 + col]; }
  else           { if (col < 136 && k < j.K[job]) v = j.W[job][(size_t)col * 128 + k]; }
  j.O[job][(size_t)col * KP + k] = f2bf(v);
}

// ---------- CSR construction ----------
__global__ void zero2(int* __restrict__ a, int na, int* __restrict__ b, int nb) {
  int i = blockIdx.x * blockDim.x + threadIdx.x;
  if (i < na) a[i] = 0;
  if (i < nb) b[i] = 0;
}
__global__ void hist2(const int* __restrict__ dc, int* __restrict__ cc,
                      const int* __restrict__ dv, int* __restrict__ cv, int nE) {
  int e = blockIdx.x * blockDim.x + threadIdx.x;
  if (e >= nE) return;
  atomicAdd(&cc[dc[e]], 1);
  atomicAdd(&cv[dv[e]], 1);
}
// single block 256 threads
__global__ void csr_scan(const int* __restrict__ counts, int* __restrict__ offsets,
                         int* __restrict__ cursor, int n) {
  __shared__ int part[256];
  int tid = threadIdx.x;
  int chunk = (n + 255) / 256;
  int lo = tid * chunk, hi = min(n, lo + chunk);
  int s = 0;
  for (int i = lo; i < hi; ++i) s += counts[i];
  part[tid] = s;
  __syncthreads();
  if (tid == 0) {
    int run = 0;
    for (int i = 0; i < 256; ++i) { int t = part[i]; part[i] = run; run += t; }
    offsets[n] = run;
  }
  __syncthreads();
  int base = part[tid];
  for (int i = lo; i < hi; ++i) { offsets[i] = base; cursor[i] = base; base += counts[i]; }
}
__global__ void csr_scatter(const int* __restrict__ dst, const int* __restrict__ src,
                            int* __restrict__ cursor, int2* __restrict__ ces, int nE) {
  int e = blockIdx.x * blockDim.x + threadIdx.x;
  if (e >= nE) return;
  int pos = atomicAdd(&cursor[dst[e]], 1);
  ces[pos] = make_int2(e, src[e]);
}

// ---------- fused flash-style segment attention: one wave per dst ----------
// ee eliminated algebraically:  q·ee = t·e with t = We@q (bf16, [Nd,160]);
// Σ a·ee = (Σ a·e)@We  -> accumulate 136-dim weighted edge sum, transform later.
// k/v are bf16 [Ns,128]. 4-edge unrolled loop for load-level parallelism.
struct AttSt { float m, l, ax, ay, axe, aye, axe2, aye2; };
__device__ __forceinline__ void att_upd(AttSt& s, float alpha, unsigned vu,
                                        float e0, float e1, float e2, float e3) {
  float mn = fmaxf(s.m, alpha);
  float scale = __expf(s.m - mn);
  float w = __expf(alpha - mn);
  s.ax = s.ax * scale + __uint_as_float(vu << 16) * w;
  s.ay = s.ay * scale + __uint_as_float(vu & 0xffff0000u) * w;
  s.axe = s.axe * scale + e0 * w;   s.aye = s.aye * scale + e1 * w;
  s.axe2 = s.axe2 * scale + e2 * w; s.aye2 = s.aye2 * scale + e3 * w;
  s.l = s.l * scale + w; s.m = mn;
}

__global__ void fused_attn(
    const float* __restrict__ qbuf, const unsigned short* __restrict__ kbuf,
    const unsigned short* __restrict__ vbuf, const unsigned short* __restrict__ tbuf,
    const unsigned short* __restrict__ ecomb,
    const int* __restrict__ offsets, const int2* __restrict__ ces,
    float* __restrict__ accVS, unsigned short* __restrict__ accE, int Nd) {
  int d = blockIdx.x * 4 + (threadIdx.x >> 6);
  if (d >= Nd) return;
  int lane = threadIdx.x & 63;
  int c = lane * 2;
  bool tl = (lane < 16);
  int c2 = 128 + c;                     // tail cols for lanes 0..15
  float2 qv = *(const float2*)&qbuf[(size_t)d * 128 + c];
  unsigned tu = *(const unsigned*)&tbuf[(size_t)d * KP + c];
  float tx = __uint_as_float(tu << 16);
  float ty = __uint_as_float(tu & 0xffff0000u);
  float tx2 = 0.f, ty2 = 0.f;
  if (tl) {
    unsigned tu2 = *(const unsigned*)&tbuf[(size_t)d * KP + c2];
    tx2 = __uint_as_float(tu2 << 16);
    ty2 = __uint_as_float(tu2 & 0xffff0000u);
  }
  int beg = offsets[d], end = offsets[d + 1];
  AttSt st{-INFINITY, 0.f, 0.f, 0.f, 0.f, 0.f, 0.f, 0.f};
  const float SC = 0.08838834764831845f;  // 1/sqrt(128)
  int i = beg;
  for (; i + 3 < end; i += 4) {
    int2 pr[4];
    pr[0] = ces[i]; pr[1] = ces[i + 1]; pr[2] = ces[i + 2]; pr[3] = ces[i + 3];
    unsigned eu[4], ku[4], vu[4];
    float e0[4], e1[4], e2[4], e3[4], p[4];
    #pragma unroll
    for (int u = 0; u < 4; ++u) {
      eu[u] = *(const unsigned*)&ecomb[(size_t)pr[u].x * KP + c];
      ku[u] = *(const unsigned*)&kbuf[(size_t)pr[u].y * 128 + c];
      vu[u] = *(const unsigned*)&vbuf[(size_t)pr[u].y * 128 + c];
    }
    #pragma unroll
    for (int u = 0; u < 4; ++u) {
      e0[u] = __uint_as_float(eu[u] << 16);
      e1[u] = __uint_as_float(eu[u] & 0xffff0000u);
      e2[u] = 0.f; e3[u] = 0.f;
    }
    if (tl) {
      #pragma unroll
      for (int u = 0; u < 4; ++u) {
        unsigned x = *(const unsigned*)&ecomb[(size_t)pr[u].x * KP + c2];
        e2[u] = __uint_as_float(x << 16);
        e3[u] = __uint_as_float(x & 0xffff0000u);
      }
    }
    #pragma unroll
    for (int u = 0; u < 4; ++u)
      p[u] = qv.x * __uint_as_float(ku[u] << 16) + qv.y * __uint_as_float(ku[u] & 0xffff0000u)
           + tx * e0[u] + ty * e1[u] + tx2 * e2[u] + ty2 * e3[u];
    #pragma unroll
    for (int off = 1; off < 64; off <<= 1) {
      p[0] += __shfl_xor(p[0], off, 64);
      p[1] += __shfl_xor(p[1], off, 64);
      p[2] += __shfl_xor(p[2], off, 64);
      p[3] += __shfl_xor(p[3], off, 64);
    }
    #pragma unroll
    for (int u = 0; u < 4; ++u)
      att_upd(st, p[u] * SC, vu[u], e0[u], e1[u], e2[u], e3[u]);
  }
  for (; i < end; ++i) {
    int2 pr = ces[i];
    unsigned eu = *(const unsigned*)&ecomb[(size_t)pr.x * KP + c];
    float e0 = __uint_as_float(eu << 16);
    float e1 = __uint_as_float(eu & 0xffff0000u);
    float e2 = 0.f, e3 = 0.f;
    if (tl) {
      unsigned x = *(const unsigned*)&ecomb[(size_t)pr.x * KP + c2];
      e2 = __uint_as_float(x << 16);
      e3 = __uint_as_float(x & 0xffff0000u);
    }
    unsigned ku = *(const unsigned*)&kbuf[(size_t)pr.y * 128 + c];
    unsigned vu = *(const unsigned*)&vbuf[(size_t)pr.y * 128 + c];
    float p = qv.x * __uint_as_float(ku << 16) + qv.y * __uint_as_float(ku & 0xffff0000u)
            + tx * e0 + ty * e1 + tx2 * e2 + ty2 * e3;
    #pragma unroll
    for (int off = 1; off < 64; off <<= 1) p += __shfl_xor(p, off, 64);
    att_upd(st, p * SC, vu, e0, e1, e2, e3);
  }
  int deg = end - beg;
  float inv = (deg > 0) ? 1.0f / (st.l * (float)deg) : 0.0f;
  float2 sk = *(const float2*)&accVS[(size_t)d * 128 + c];
  *(float2*)&accVS[(size_t)d * 128 + c] =
      make_float2(st.ax * inv + sk.x, st.ay * inv + sk.y);
  ushort2 oe; oe.x = f2bf(st.axe * inv); oe.y = f2bf(st.aye * inv);
  *(ushort2*)&accE[(size_t)d * KP + c] = oe;
  if (tl) {
    ushort2 oe2; oe2.x = f2bf(st.axe2 * inv); oe2.y = f2bf(st.aye2 * inv);
    *(ushort2*)&accE[(size_t)d * KP + c2] = oe2;
  }
}

extern "C" void kernel_launch(void* const* d_in, const int* in_sizes, int n_in,
                              void* d_out, int out_size, void* d_ws, size_t ws_size,
                              hipStream_t stream) {
  const float* var_learned = (const float*)d_in[0];
  const float* var_lp      = (const float*)d_in[1];
  const float* con_learned = (const float*)d_in[2];
  const float* con_lp      = (const float*)d_in[3];
  const float* edge_learned= (const float*)d_in[4];
  const float* lo          = (const float*)d_in[5];
  const float* hi          = (const float*)d_in[6];
  const float* dm          = (const float*)d_in[7];
  const float* wo          = (const float*)d_in[8];
  const float* cu_Wq = (const float*)d_in[9],  *cu_bq = (const float*)d_in[10];
  const float* cu_Wk = (const float*)d_in[11], *cu_bk = (const float*)d_in[12];
  const float* cu_Wv = (const float*)d_in[13], *cu_bv = (const float*)d_in[14];
  const float* cu_We = (const float*)d_in[15];
  const float* cu_Ws = (const float*)d_in[16], *cu_bs = (const float*)d_in[17];
  const float* vu_Wq = (const float*)d_in[18], *vu_bq = (const float*)d_in[19];
  const float* vu_Wk = (const float*)d_in[20], *vu_bk = (const float*)d_in[21];
  const float* vu_Wv = (const float*)d_in[22], *vu_bv = (const float*)d_in[23];
  const float* vu_We = (const float*)d_in[24];
  const float* vu_Ws = (const float*)d_in[25], *vu_bs = (const float*)d_in[26];
  const float* eu_vW1 = (const float*)d_in[27], *eu_vb1 = (const float*)d_in[28];
  const float* eu_vW2 = (const float*)d_in[29], *eu_vb2 = (const float*)d_in[30];
  const float* eu_cW1 = (const float*)d_in[31], *eu_cb1 = (const float*)d_in[32];
  const float* eu_cW2 = (const float*)d_in[33], *eu_cb2 = (const float*)d_in[34];
  const float* eu_eW1 = (const float*)d_in[35], *eu_eb1 = (const float*)d_in[36];
  const float* eu_eW2 = (const float*)d_in[37], *eu_eb2 = (const float*)d_in[38];
  const int* eiv = (const int*)d_in[39];
  const int* eic = (const int*)d_in[40];

  float* out_var  = (float*)d_out;
  float* out_con  = out_var + (size_t)NVV * 128;
  float* out_edge = out_con + (size_t)NCC * 128;

  // ---- workspace arena ----
  char* w = (char*)d_ws;
  auto alloc = [&](size_t bytes) { char* p = w; w += (bytes + 255) & ~(size_t)255; return p; };
  unsigned short* edge_comb_bf = (unsigned short*)alloc((size_t)NEE * KP * 2);  // 80MB
  unsigned short* var_comb_bf = (unsigned short*)alloc((size_t)NVV * KP * 2);
  unsigned short* con_comb_bf = (unsigned short*)alloc((size_t)NCC * KP * 2);
  unsigned short* q_bf    = (unsigned short*)alloc((size_t)NVV * KP * 2);
  unsigned short* t_bf    = (unsigned short*)alloc((size_t)NVV * KP * 2);
  unsigned short* accE_bf = (unsigned short*)alloc((size_t)NVV * KP * 2);
  unsigned short* kv_bf   = (unsigned short*)alloc((size_t)NVV * 128 * 2);
  unsigned short* vv_bf   = (unsigned short*)alloc((size_t)NVV * 128 * 2);
  unsigned short* vc_bf   = (unsigned short*)alloc((size_t)NVV * 128 * 2);
  unsigned short* cc_bf   = (unsigned short*)alloc((size_t)NCC * 128 * 2);
  float* bufV1 = (float*)alloc((size_t)NVV * 128 * 4);
  float* bufV2 = (float*)alloc((size_t)NVV * 128 * 4);
  float* bufC1 = (float*)alloc((size_t)NCC * 128 * 4);
  float* bufC2 = (float*)alloc((size_t)NCC * 128 * 4);
  unsigned short* WTbase = (unsigned short*)alloc((size_t)20 * 160 * KP * 2);
  int* countsC = (int*)alloc((size_t)NCC * 4);
  int* countsV = (int*)alloc((size_t)NVV * 4);
  int* offC = (int*)alloc((size_t)(NCC + 1) * 4);
  int* curC = (int*)alloc((size_t)NCC * 4);
  int* offV = (int*)alloc((size_t)(NVV + 1) * 4);
  int* curV = (int*)alloc((size_t)NVV * 4);
  int2* cesA = (int2*)alloc((size_t)NEE * 8);  // conv A (dst=con): {edge, src}
  int2* cesB = (int2*)alloc((size_t)NEE * 8);  // conv B (dst=var)
  (void)ws_size; (void)in_sizes; (void)n_in; (void)out_size;

  unsigned short* WT[20];
  for (int i = 0; i < 20; ++i) WT[i] = WTbase + (size_t)i * 160 * KP;
  WJobs jobs;
  const float* Wsrc[20] = {cu_Wq, cu_Wk, cu_Wv, cu_We, cu_Ws,
                           vu_Wq, vu_Wk, vu_Wv, vu_We, vu_Ws,
                           eu_vW1, eu_vW2, eu_cW1, eu_cW2,
                           eu_eW1, eu_eW1 + 136 * 128, eu_eW1 + 264 * 128, eu_eW2,
                           cu_We, vu_We};
  const int Ksrc[20] = {144, 144, 144, 136, 144, 144, 144, 144, 136, 144,
                        144, 128, 144, 128, 136, 128, 128, 128, 128, 128};
  const int Tsrc[20] = {1,1,1,1,1, 1,1,1,1,1, 1,1,1,1, 1,1,1,1, 0,0};
  for (int i = 0; i < 20; ++i) {
    jobs.W[i] = Wsrc[i]; jobs.O[i] = WT[i]; jobs.K[i] = Ksrc[i]; jobs.TR[i] = Tsrc[i];
  }

  const int T = 256;
  const int NBC = (NCC + 63) / 64;   // 196
  const int NBV = (NVV + 63) / 64;   // 391
  const int NBE = (NEE + 63) / 64;   // 3907

  // ---- pre-passes ----
  build_node_bf<<<(NVV * 40 + T - 1) / T, T, 0, stream>>>(var_learned, var_lp, var_comb_bf, NVV);
  build_node_bf<<<(NCC * 40 + T - 1) / T, T, 0, stream>>>(con_learned, con_lp, con_comb_bf, NCC);
  build_edge_bf<<<(NEE * 40 + T - 1) / T, T, 0, stream>>>(edge_learned, lo, hi, dm, wo, edge_comb_bf);
  convert_weights<<<20 * 100, T, 0, stream>>>(jobs);

  // ---- CSR builds ----
  zero2<<<(NVV + T - 1) / T, T, 0, stream>>>(countsC, NCC, countsV, NVV);
  hist2<<<(NEE + T - 1) / T, T, 0, stream>>>(eic, countsC, eiv, countsV, NEE);
  csr_scan<<<1, 256, 0, stream>>>(countsC, offC, curC, NCC);
  csr_scan<<<1, 256, 0, stream>>>(countsV, offV, curV, NVV);
  csr_scatter<<<(NEE + T - 1) / T, T, 0, stream>>>(eic, eiv, curC, cesA, NEE);
  csr_scatter<<<(NEE + T - 1) / T, T, 0, stream>>>(eiv, eic, curV, cesB, NEE);

  // ================= Stage A: con update (src=var, dst=con) =================
  {
    GBatch b{};
    b.j[0] = {con_comb_bf, WT[0], cu_bq, nullptr, bufC1, q_bf, KP, 1, NCC, 0};   // q_c
    b.j[1] = {con_comb_bf, WT[4], cu_bs, nullptr, bufC2, nullptr, 0, 0, NCC, 0}; // skip_c
    b.j[2] = {var_comb_bf, WT[1], cu_bk, nullptr, nullptr, kv_bf, 128, 0, NVV, 0}; // k_v
    b.j[3] = {var_comb_bf, WT[2], cu_bv, nullptr, nullptr, vv_bf, 128, 0, NVV, 0}; // v_v
    b.start[0] = 0; b.start[1] = NBC; b.start[2] = 2 * NBC; b.start[3] = 2 * NBC + NBV;
    b.njobs = 4;
    gemm_batch<<<2 * NBC + 2 * NBV, 256, 0, stream>>>(b);
  }
  gemm_t<<<NBC, 256, 0, stream>>>(q_bf, WT[18], t_bf, NCC);   // t_c = We @ q_c
  fused_attn<<<(NCC + 3) / 4, 256, 0, stream>>>(bufC1, kv_bf, vv_bf, t_bf, edge_comb_bf,
                                                offC, cesA, bufC2, accE_bf, NCC);
  {
    GBatch b{};
    b.j[0] = {accE_bf, WT[3], nullptr, bufC2, out_con, con_comb_bf, KP, 0, NCC, 1};
    b.start[0] = 0; b.njobs = 1;
    gemm_batch<<<NBC, 256, 0, stream>>>(b);    // con_new = relu(accE@We + accVS)
  }

  // ================= Stage B: var update (src=new con, dst=var) =================
  {
    GBatch b{};
    b.j[0] = {var_comb_bf, WT[5], vu_bq, nullptr, bufV1, q_bf, KP, 1, NVV, 0};   // q_v
    b.j[1] = {var_comb_bf, WT[9], vu_bs, nullptr, bufV2, nullptr, 0, 0, NVV, 0}; // skip_v
    b.j[2] = {con_comb_bf, WT[6], vu_bk, nullptr, nullptr, kv_bf, 128, 0, NCC, 0}; // k_c
    b.j[3] = {con_comb_bf, WT[7], vu_bv, nullptr, nullptr, vv_bf, 128, 0, NCC, 0}; // v_c
    b.start[0] = 0; b.start[1] = NBV; b.start[2] = 2 * NBV; b.start[3] = 2 * NBV + NBC;
    b.njobs = 4;
    gemm_batch<<<2 * NBV + 2 * NBC, 256, 0, stream>>>(b);
  }
  gemm_t<<<NBV, 256, 0, stream>>>(q_bf, WT[19], t_bf, NVV);   // t_v = We @ q_v
  fused_attn<<<(NVV + 3) / 4, 256, 0, stream>>>(bufV1, kv_bf, vv_bf, t_bf, edge_comb_bf,
                                                offV, cesB, bufV2, accE_bf, NVV);
  {
    GBatch b{};
    b.j[0] = {accE_bf, WT[8], nullptr, bufV2, out_var, var_comb_bf, KP, 0, NVV, 1};
    b.start[0] = 0; b.njobs = 1;
    gemm_batch<<<NBV, 256, 0, stream>>>(b);    // var_new = relu(accE@We + accVS)
  }

  // ================= Edge stage (fully chained) =================
  gemm_chain<<<NBV, 256, 0, stream>>>(
      var_comb_bf, WT[10], eu_vb1, nullptr, nullptr, nullptr, nullptr,
      WT[11], eu_vb2, WT[15], nullptr, nullptr, vc_bf, NVV, 0);   // vcW (bf16)
  gemm_chain<<<NBC, 256, 0, stream>>>(
      con_comb_bf, WT[12], eu_cb1, nullptr, nullptr, nullptr, nullptr,
      WT[13], eu_cb2, WT[16], nullptr, nullptr, cc_bf, NCC, 0);   // ccW (bf16)
  gemm_chain<<<NBE, 256, 0, stream>>>(
      edge_comb_bf, WT[14], eu_eb1, vc_bf, cc_bf, eiv, eic,
      WT[17], eu_eb2, nullptr, nullptr, out_edge, nullptr, NEE, 1);  // edge_new
}

// Round 6
// 775.338 us; speedup vs baseline: 1.2129x; 1.0727x over previous
//
#include <hip/hip_runtime.h>
#include <math.h>

#define NVV 25000
#define NCC 12500
#define NEE 250000
#define KP 160   // padded K for all bf16 GEMM inputs (covers K=128,136,144)

typedef short bf16x8 __attribute__((ext_vector_type(8)));
typedef float f32x4 __attribute__((ext_vector_type(4)));

// ---------- helpers ----------
__device__ __forceinline__ unsigned short f2bf(float f) {  // RNE fp32->bf16
  unsigned u = __float_as_uint(f);
  u += 0x7fffu + ((u >> 16) & 1u);
  return (unsigned short)(u >> 16);
}
__device__ __forceinline__ float bf2f(unsigned short u) {
  return __uint_as_float((unsigned)u << 16);
}
__device__ __forceinline__ void gll16(const unsigned short* g, unsigned short* l) {
  __builtin_amdgcn_global_load_lds(
      (const __attribute__((address_space(1))) unsigned int*)(const void*)g,
      (__attribute__((address_space(3))) unsigned int*)(void*)l, 16, 0, 0);
}

// Stage a 64-row x 160-k bf16 strip (20KB) into LDS chunk layout [kk][row64][32].
__device__ __forceinline__ void stage_rows64(const unsigned short* __restrict__ X,
                                             unsigned short* As, int row0, int N,
                                             int wave, int lane) {
  #pragma unroll
  for (int j = 0; j < 5; ++j) {
    int inst = wave * 5 + j;                 // 0..19
    int L = inst * 1024 + lane * 16;         // byte offset in As
    int kk = L >> 12;                        // 4096B per chunk (64 rows x 64B)
    int r = (L >> 6) & 63;
    int ks = (L & 63) >> 1;
    int grow = row0 + r; if (grow >= N) grow = N - 1;
    gll16(X + (size_t)grow * KP + kk * 32 + ks, As + inst * 512);
  }
}

template <int MI, int NI>
__device__ __forceinline__ void zero_acc(f32x4 (&acc)[MI][NI]) {
  #pragma unroll
  for (int mi = 0; mi < MI; ++mi)
    #pragma unroll
    for (int ni = 0; ni < NI; ++ni) {
      acc[mi][ni][0] = 0.f; acc[mi][ni][1] = 0.f;
      acc[mi][ni][2] = 0.f; acc[mi][ni][3] = 0.f;
    }
}

// One K-chunk (32) of MFMA: A fragments from LDS, B fragments from global
// (weights are a 40KB L2-hot table shared by all blocks).
template <int MI, int NI>
__device__ __forceinline__ void chunk_mfma_g(const unsigned short* As,
                                             const unsigned short* __restrict__ WT,
                                             f32x4 (&acc)[MI][NI], int kk,
                                             int wm, int wn, int fr, int fq) {
  bf16x8 av[MI], bv[NI];
  #pragma unroll
  for (int mi = 0; mi < MI; ++mi)
    av[mi] = *(const bf16x8*)&As[kk * 2048 + (wm + mi * 16 + fr) * 32 + fq * 8];
  #pragma unroll
  for (int ni = 0; ni < NI; ++ni)
    bv[ni] = *(const bf16x8*)&WT[(size_t)(wn + ni * 16 + fr) * KP + kk * 32 + fq * 8];
  #pragma unroll
  for (int mi = 0; mi < MI; ++mi)
    #pragma unroll
    for (int ni = 0; ni < NI; ++ni)
      acc[mi][ni] = __builtin_amdgcn_mfma_f32_16x16x32_bf16(av[mi], bv[ni],
                                                            acc[mi][ni], 0, 0, 0);
}

// ---------- batched bf16 MFMA GEMM: out[N,128] = X[N,160] @ WT^T ----------
struct GJob {
  const unsigned short* X; const unsigned short* WT;
  const float* bias; const float* addf;
  float* outf; unsigned short* outb;
  int outb_stride, pad_flag, N, relu_flag;
  int ntf;   // non-temporal f32 store (final outputs)
};
struct GBatch { GJob j[4]; int start[4]; int njobs; };

// regs ~92 (32 AGPR acc + ~60 VGPR) -> (256,4): cap 128, spill-free optimum.
__global__ __launch_bounds__(256, 4) void gemm_batch(GBatch B) {
  int job = 0;
  #pragma unroll
  for (int t = 1; t < 4; ++t)
    if (t < B.njobs && (int)blockIdx.x >= B.start[t]) job = t;
  GJob g = B.j[job];
  __shared__ unsigned short As[5 * 64 * 32];   // 20 KB
  const int tid = threadIdx.x;
  const int lane = tid & 63, wave = tid >> 6;
  const int row0 = (blockIdx.x - B.start[job]) * 64;
  const int wm = (wave & 1) * 32, wn = (wave >> 1) * 64;
  const int fr = lane & 15, fq = lane >> 4;

  stage_rows64(g.X, As, row0, g.N, wave, lane);
  f32x4 acc[2][4];
  zero_acc<2, 4>(acc);
  __syncthreads();
  #pragma unroll
  for (int kk = 0; kk < 5; ++kk) chunk_mfma_g<2, 4>(As, g.WT, acc, kk, wm, wn, fr, fq);

  #pragma unroll
  for (int mi = 0; mi < 2; ++mi) {
    #pragma unroll
    for (int ni = 0; ni < 4; ++ni) {
      int gcol = wn + ni * 16 + fr;
      float bvv = g.bias ? g.bias[gcol] : 0.0f;
      #pragma unroll
      for (int r = 0; r < 4; ++r) {
        int grow = row0 + wm + mi * 16 + fq * 4 + r;
        if (grow < g.N) {
          float o = acc[mi][ni][r] + bvv;
          if (g.addf) o += g.addf[(size_t)grow * 128 + gcol];
          if (g.relu_flag) o = fmaxf(o, 0.f);
          if (g.outf) {
            if (g.ntf) __builtin_nontemporal_store(o, &g.outf[(size_t)grow * 128 + gcol]);
            else       g.outf[(size_t)grow * 128 + gcol] = o;
          }
          if (g.outb) g.outb[(size_t)grow * g.outb_stride + gcol] = f2bf(o);
        }
      }
    }
    if (g.outb && g.pad_flag && wn == 0) {
      #pragma unroll
      for (int r = 0; r < 4; ++r) {
        int grow = row0 + wm + mi * 16 + fq * 4 + r;
        if (grow < g.N)
          for (int pc = 128 + fr; pc < g.outb_stride; pc += 16)
            g.outb[(size_t)grow * g.outb_stride + pc] = 0;
      }
    }
  }
}

// ---------- fused q->t kernel, batched over both convs ----------
// stage1: q = X@Wq + bq  -> qf (f32, for attn)  and bf16 T2 in LDS
// stage2: t = q@Wt'      -> tb (bf16, stride KP, 160 cols; cols>=136 are 0)
struct QTJob {
  const unsigned short* X; const unsigned short* Wq; const float* bq;
  const unsigned short* Wt; float* qf; unsigned short* tb; int N;
};
struct QTBatch { QTJob j[2]; int start; };

__global__ __launch_bounds__(256, 4) void gemm_qt(QTBatch B) {
  int job = ((int)blockIdx.x >= B.start) ? 1 : 0;
  QTJob g = B.j[job];
  __shared__ unsigned short As[5 * 64 * 32];
  const int tid = threadIdx.x;
  const int lane = tid & 63, wave = tid >> 6;
  const int row0 = (blockIdx.x - (job ? B.start : 0)) * 64;
  const int wm = (wave & 1) * 32;
  const int fr = lane & 15, fq = lane >> 4;

  stage_rows64(g.X, As, row0, g.N, wave, lane);
  {
    const int wn = (wave >> 1) * 64;
    f32x4 acc[2][4];
    zero_acc<2, 4>(acc);
    __syncthreads();
    #pragma unroll
    for (int kk = 0; kk < 5; ++kk) chunk_mfma_g<2, 4>(As, g.Wq, acc, kk, wm, wn, fr, fq);
    __syncthreads();                   // stage-1 LDS reads done
    #pragma unroll
    for (int mi = 0; mi < 2; ++mi)
      #pragma unroll
      for (int ni = 0; ni < 4; ++ni) {
        int col = wn + ni * 16 + fr;
        float bvv = g.bq[col];
        #pragma unroll
        for (int r = 0; r < 4; ++r) {
          int row = wm + mi * 16 + fq * 4 + r;
          int grow = row0 + row;
          float o = acc[mi][ni][r] + bvv;
          if (grow < g.N) g.qf[(size_t)grow * 128 + col] = o;
          As[(col >> 5) * 2048 + row * 32 + (col & 31)] = f2bf(o);
        }
      }
  }
  __syncthreads();                     // T2 visible
  {
    const int wn = (wave >> 1) * 80;   // NI=5 layout
    f32x4 acc[2][5];
    zero_acc<2, 5>(acc);
    #pragma unroll
    for (int kk = 0; kk < 4; ++kk) chunk_mfma_g<2, 5>(As, g.Wt, acc, kk, wm, wn, fr, fq);
    #pragma unroll
    for (int mi = 0; mi < 2; ++mi)
      #pragma unroll
      for (int ni = 0; ni < 5; ++ni) {
        int gcol = wn + ni * 16 + fr;
        #pragma unroll
        for (int r = 0; r < 4; ++r) {
          int grow = row0 + wm + mi * 16 + fq * 4 + r;
          if (grow < g.N) g.tb[(size_t)grow * KP + gcol] = f2bf(acc[mi][ni][r]);
        }
      }
  }
}

// ---------- chained GEMM (3-stage, node compress paths) ----------
__global__ __launch_bounds__(256, 4) void gemm_chain(
    const unsigned short* __restrict__ X,
    const unsigned short* __restrict__ W1, const float* __restrict__ b1,
    const unsigned short* __restrict__ W2, const float* __restrict__ b2,
    const unsigned short* __restrict__ W3,
    unsigned short* __restrict__ outw, int N) {
  __shared__ unsigned short As[5 * 64 * 32];   // 20 KB, reused for T2
  const int tid = threadIdx.x;
  const int lane = tid & 63, wave = tid >> 6;
  const int row0 = blockIdx.x * 64;
  const int wm = (wave & 1) * 32, wn = (wave >> 1) * 64;
  const int fr = lane & 15, fq = lane >> 4;

  stage_rows64(X, As, row0, N, wave, lane);
  f32x4 acc[2][4];
  zero_acc<2, 4>(acc);
  __syncthreads();
  #pragma unroll
  for (int kk = 0; kk < 5; ++kk) chunk_mfma_g<2, 4>(As, W1, acc, kk, wm, wn, fr, fq);

  __syncthreads();
  #pragma unroll
  for (int mi = 0; mi < 2; ++mi)
    #pragma unroll
    for (int ni = 0; ni < 4; ++ni) {
      int col = wn + ni * 16 + fr;
      float bvv = b1[col];
      #pragma unroll
      for (int r = 0; r < 4; ++r) {
        int row = wm + mi * 16 + fq * 4 + r;
        float o = fmaxf(acc[mi][ni][r] + bvv, 0.f);
        As[(col >> 5) * 2048 + row * 32 + (col & 31)] = f2bf(o);
      }
    }
  zero_acc<2, 4>(acc);
  __syncthreads();

  #pragma unroll
  for (int kk = 0; kk < 4; ++kk) chunk_mfma_g<2, 4>(As, W2, acc, kk, wm, wn, fr, fq);

  __syncthreads();
  #pragma unroll
  for (int mi = 0; mi < 2; ++mi)
    #pragma unroll
    for (int ni = 0; ni < 4; ++ni) {
      int col = wn + ni * 16 + fr;
      float bvv = b2[col];
      #pragma unroll
      for (int r = 0; r < 4; ++r) {
        int row = wm + mi * 16 + fq * 4 + r;
        float o = fmaxf(acc[mi][ni][r] + bvv, 0.f);
        As[(col >> 5) * 2048 + row * 32 + (col & 31)] = f2bf(o);
      }
    }
  zero_acc<2, 4>(acc);
  __syncthreads();
  #pragma unroll
  for (int kk = 0; kk < 4; ++kk) chunk_mfma_g<2, 4>(As, W3, acc, kk, wm, wn, fr, fq);
  #pragma unroll
  for (int mi = 0; mi < 2; ++mi)
    #pragma unroll
    for (int ni = 0; ni < 4; ++ni) {
      int gcol = wn + ni * 16 + fr;
      #pragma unroll
      for (int r = 0; r < 4; ++r) {
        int grow = row0 + wm + mi * 16 + fq * 4 + r;
        if (grow < N) outw[(size_t)grow * 128 + gcol] = f2bf(acc[mi][ni][r]);
      }
    }
}

// ---------- edge kernel: 2-tile pipelined, 2-stage chained ----------
__device__ __forceinline__ void edge_epi(unsigned short* L, const f32x4 (&acc)[2][4],
    int rbase, int N, const float* __restrict__ b1,
    const unsigned short* __restrict__ gA, const unsigned short* __restrict__ gB,
    const int* __restrict__ giA, const int* __restrict__ giB,
    int wm, int wn, int fr, int fq) {
  #pragma unroll
  for (int mi = 0; mi < 2; ++mi)
    #pragma unroll
    for (int ni = 0; ni < 4; ++ni) {
      int col = wn + ni * 16 + fr;
      float bvv = b1[col];
      #pragma unroll
      for (int r = 0; r < 4; ++r) {
        int row = wm + mi * 16 + fq * 4 + r;
        int grow = rbase + row;
        int gi = (grow < N) ? grow : (N - 1);
        float o = acc[mi][ni][r] + bvv
                + bf2f(gA[(size_t)giA[gi] * 128 + col])
                + bf2f(gB[(size_t)giB[gi] * 128 + col]);
        o = fmaxf(o, 0.f);
        L[(col >> 5) * 2048 + row * 32 + (col & 31)] = f2bf(o);
      }
    }
}
__device__ __forceinline__ void edge_store(const f32x4 (&acc)[2][4], int rbase, int N,
    const float* __restrict__ b2, float* __restrict__ outf,
    int wm, int wn, int fr, int fq) {
  #pragma unroll
  for (int mi = 0; mi < 2; ++mi)
    #pragma unroll
    for (int ni = 0; ni < 4; ++ni) {
      int gcol = wn + ni * 16 + fr;
      float bvv = b2[gcol];
      #pragma unroll
      for (int r = 0; r < 4; ++r) {
        int grow = rbase + wm + mi * 16 + fq * 4 + r;
        if (grow < N) {
          float o = fmaxf(acc[mi][ni][r] + bvv, 0.f);
          __builtin_nontemporal_store(o, &outf[(size_t)grow * 128 + gcol]);
        }
      }
    }
}

__global__ __launch_bounds__(256, 4) void gemm_edge2(
    const unsigned short* __restrict__ X,
    const unsigned short* __restrict__ W1, const float* __restrict__ b1,
    const unsigned short* __restrict__ gA, const unsigned short* __restrict__ gB,
    const int* __restrict__ giA, const int* __restrict__ giB,
    const unsigned short* __restrict__ W2, const float* __restrict__ b2,
    float* __restrict__ outf, int N) {
  __shared__ unsigned short As[5 * 64 * 32];   // tile A (20 KB)
  __shared__ unsigned short Bs[5 * 64 * 32];   // tile B (20 KB)
  const int tid = threadIdx.x;
  const int lane = tid & 63, wave = tid >> 6;
  const int row0 = blockIdx.x * 128;
  const int wm = (wave & 1) * 32, wn = (wave >> 1) * 64;
  const int fr = lane & 15, fq = lane >> 4;

  stage_rows64(X, As, row0, N, wave, lane);
  f32x4 acc[2][4];
  zero_acc<2, 4>(acc);
  __syncthreads();                               // A resident
  stage_rows64(X, Bs, row0 + 64, N, wave, lane); // issue B; latency hides under A's work

  // ---- tile A ----
  #pragma unroll
  for (int kk = 0; kk < 5; ++kk) chunk_mfma_g<2, 4>(As, W1, acc, kk, wm, wn, fr, fq);
  __syncthreads();                               // A reads done; B resident too
  edge_epi(As, acc, row0, N, b1, gA, gB, giA, giB, wm, wn, fr, fq);
  zero_acc<2, 4>(acc);
  __syncthreads();
  #pragma unroll
  for (int kk = 0; kk < 4; ++kk) chunk_mfma_g<2, 4>(As, W2, acc, kk, wm, wn, fr, fq);
  edge_store(acc, row0, N, b2, outf, wm, wn, fr, fq);

  // ---- tile B ----
  zero_acc<2, 4>(acc);
  #pragma unroll
  for (int kk = 0; kk < 5; ++kk) chunk_mfma_g<2, 4>(Bs, W1, acc, kk, wm, wn, fr, fq);
  __syncthreads();
  edge_epi(Bs, acc, row0 + 64, N, b1, gA, gB, giA, giB, wm, wn, fr, fq);
  zero_acc<2, 4>(acc);
  __syncthreads();
  #pragma unroll
  for (int kk = 0; kk < 4; ++kk) chunk_mfma_g<2, 4>(Bs, W2, acc, kk, wm, wn, fr, fq);
  edge_store(acc, row0 + 64, N, b2, outf, wm, wn, fr, fq);
}

// ---------- build bf16 combined features ----------
__global__ void build_node_bf(const float* __restrict__ learned, const float* __restrict__ lp,
                              unsigned short* __restrict__ out, int N) {
  int idx = blockIdx.x * blockDim.x + threadIdx.x;
  if (idx >= N * 40) return;
  int row = idx / 40, c4 = idx - row * 40;
  int c = c4 * 4;
  ushort4 o;
  if (c4 < 32) {
    const float* p = learned + (size_t)row * 128 + c;
    o.x = f2bf(p[0]); o.y = f2bf(p[1]); o.z = f2bf(p[2]); o.w = f2bf(p[3]);
  } else if (c4 < 36) {
    const float* p = lp + (size_t)row * 16 + (c - 128);
    o.x = f2bf(p[0]); o.y = f2bf(p[1]); o.z = f2bf(p[2]); o.w = f2bf(p[3]);
  } else { o.x = o.y = o.z = o.w = 0; }
  *(ushort4*)&out[(size_t)row * KP + c] = o;
}

__global__ void build_edge_bf(const float* __restrict__ el, const float* __restrict__ lo,
                              const float* __restrict__ hi, const float* __restrict__ dm,
                              const float* __restrict__ wo, unsigned short* __restrict__ out) {
  int idx = blockIdx.x * blockDim.x + threadIdx.x;
  if (idx >= NEE * 40) return;
  int row = idx / 40, c4 = idx - row * 40;
  int c = c4 * 4;
  ushort4 o;
  if (c4 < 32) {
    const float* p = el + (size_t)row * 128 + c;
    o.x = f2bf(p[0]); o.y = f2bf(p[1]); o.z = f2bf(p[2]); o.w = f2bf(p[3]);
  } else if (c4 == 32) {
    o.x = f2bf(lo[row]); o.y = f2bf(hi[row]); o.z = f2bf(dm[row]);
    o.w = f2bf(wo[(size_t)row * 5 + 0]);
  } else if (c4 == 33) {
    const float* p = wo + (size_t)row * 5;
    o.x = f2bf(p[1]); o.y = f2bf(p[2]); o.z = f2bf(p[3]); o.w = f2bf(p[4]);
  } else { o.x = o.y = o.z = o.w = 0; }
  *(ushort4*)&out[(size_t)row * KP + c] = o;
}

// ---------- weight transpose/copy + convert ----------
struct WJobs {
  const float* W[20];
  unsigned short* O[20];
  int K[20];
  int TR[20];
};
__global__ void convert_weights(WJobs j) {
  int b = blockIdx.x;
  int job = b / 100;
  int i = (b - job * 100) * 256 + threadIdx.x;   // 0 .. 160*KP
  int col = i / KP;
  int k = i - col * KP;
  float v = 0.f;
  if (j.TR[job]) { if (col < 128 && k < j.K[job]) v = j.W[job][(size_t)k * 128 + col]; }
  else           { if (col < 136 && k < j.K[job]) v = j.W[job][(size_t)col * 128 + k]; }
  j.O[job][(size_t)col * KP + k] = f2bf(v);
}

// ---------- CSR construction ----------
__global__ void zero2(int* __restrict__ a, int na, int* __restrict__ b, int nb) {
  int i = blockIdx.x * blockDim.x + threadIdx.x;
  if (i < na) a[i] = 0;
  if (i < nb) b[i] = 0;
}
__global__ void hist2(const int* __restrict__ dc, int* __restrict__ cc,
                      const int* __restrict__ dv, int* __restrict__ cv, int nE) {
  int e = blockIdx.x * blockDim.x + threadIdx.x;
  if (e >= nE) return;
  atomicAdd(&cc[dc[e]], 1);
  atomicAdd(&cv[dv[e]], 1);
}
__global__ void csr_scan(const int* __restrict__ counts, int* __restrict__ offsets,
                         int* __restrict__ cursor, int n) {
  __shared__ int part[256];
  int tid = threadIdx.x;
  int chunk = (n + 255) / 256;
  int lo = tid * chunk, hi = min(n, lo + chunk);
  int s = 0;
  for (int i = lo; i < hi; ++i) s += counts[i];
  part[tid] = s;
  __syncthreads();
  if (tid == 0) {
    int run = 0;
    for (int i = 0; i < 256; ++i) { int t = part[i]; part[i] = run; run += t; }
    offsets[n] = run;
  }
  __syncthreads();
  int base = part[tid];
  for (int i = lo; i < hi; ++i) { offsets[i] = base; cursor[i] = base; base += counts[i]; }
}
__global__ void csr_scatter(const int* __restrict__ dst, const int* __restrict__ src,
                            int* __restrict__ cursor, int2* __restrict__ ces, int nE) {
  int e = blockIdx.x * blockDim.x + threadIdx.x;
  if (e >= nE) return;
  int pos = atomicAdd(&cursor[dst[e]], 1);
  ces[pos] = make_int2(e, src[e]);
}

// ---------- fused flash-style segment attention: one wave per dst ----------
struct AttSt { float m, l, ax, ay, axe, aye, axe2, aye2; };
__device__ __forceinline__ void att_upd(AttSt& s, float alpha, unsigned vu,
                                        float e0, float e1, float e2, float e3) {
  float mn = fmaxf(s.m, alpha);
  float scale = __expf(s.m - mn);
  float w = __expf(alpha - mn);
  s.ax = s.ax * scale + __uint_as_float(vu << 16) * w;
  s.ay = s.ay * scale + __uint_as_float(vu & 0xffff0000u) * w;
  s.axe = s.axe * scale + e0 * w;   s.aye = s.aye * scale + e1 * w;
  s.axe2 = s.axe2 * scale + e2 * w; s.aye2 = s.aye2 * scale + e3 * w;
  s.l = s.l * scale + w; s.m = mn;
}

__global__ void fused_attn(
    const float* __restrict__ qbuf, const unsigned short* __restrict__ kbuf,
    const unsigned short* __restrict__ vbuf, const unsigned short* __restrict__ tbuf,
    const unsigned short* __restrict__ ecomb,
    const int* __restrict__ offsets, const int2* __restrict__ ces,
    float* __restrict__ accVS, unsigned short* __restrict__ accE, int Nd) {
  int d = blockIdx.x * 4 + (threadIdx.x >> 6);
  if (d >= Nd) return;
  int lane = threadIdx.x & 63;
  int c = lane * 2;
  bool tl = (lane < 16);
  int c2 = 128 + c;
  float2 qv = *(const float2*)&qbuf[(size_t)d * 128 + c];
  unsigned tu = *(const unsigned*)&tbuf[(size_t)d * KP + c];
  float tx = __uint_as_float(tu << 16);
  float ty = __uint_as_float(tu & 0xffff0000u);
  float tx2 = 0.f, ty2 = 0.f;
  if (tl) {
    unsigned tu2 = *(const unsigned*)&tbuf[(size_t)d * KP + c2];
    tx2 = __uint_as_float(tu2 << 16);
    ty2 = __uint_as_float(tu2 & 0xffff0000u);
  }
  int beg = offsets[d], end = offsets[d + 1];
  AttSt st{-INFINITY, 0.f, 0.f, 0.f, 0.f, 0.f, 0.f, 0.f};
  const float SC = 0.08838834764831845f;  // 1/sqrt(128)
  int i = beg;
  for (; i + 3 < end; i += 4) {
    int2 pr[4];
    pr[0] = ces[i]; pr[1] = ces[i + 1]; pr[2] = ces[i + 2]; pr[3] = ces[i + 3];
    unsigned eu[4], ku[4], vu[4];
    float e0[4], e1[4], e2[4], e3[4], p[4];
    #pragma unroll
    for (int u = 0; u < 4; ++u) {
      eu[u] = *(const unsigned*)&ecomb[(size_t)pr[u].x * KP + c];
      ku[u] = *(const unsigned*)&kbuf[(size_t)pr[u].y * 128 + c];
      vu[u] = *(const unsigned*)&vbuf[(size_t)pr[u].y * 128 + c];
    }
    #pragma unroll
    for (int u = 0; u < 4; ++u) {
      e0[u] = __uint_as_float(eu[u] << 16);
      e1[u] = __uint_as_float(eu[u] & 0xffff0000u);
      e2[u] = 0.f; e3[u] = 0.f;
    }
    if (tl) {
      #pragma unroll
      for (int u = 0; u < 4; ++u) {
        unsigned x = *(const unsigned*)&ecomb[(size_t)pr[u].x * KP + c2];
        e2[u] = __uint_as_float(x << 16);
        e3[u] = __uint_as_float(x & 0xffff0000u);
      }
    }
    #pragma unroll
    for (int u = 0; u < 4; ++u)
      p[u] = qv.x * __uint_as_float(ku[u] << 16) + qv.y * __uint_as_float(ku[u] & 0xffff0000u)
           + tx * e0[u] + ty * e1[u] + tx2 * e2[u] + ty2 * e3[u];
    #pragma unroll
    for (int off = 1; off < 64; off <<= 1) {
      p[0] += __shfl_xor(p[0], off, 64);
      p[1] += __shfl_xor(p[1], off, 64);
      p[2] += __shfl_xor(p[2], off, 64);
      p[3] += __shfl_xor(p[3], off, 64);
    }
    #pragma unroll
    for (int u = 0; u < 4; ++u)
      att_upd(st, p[u] * SC, vu[u], e0[u], e1[u], e2[u], e3[u]);
  }
  for (; i < end; ++i) {
    int2 pr = ces[i];
    unsigned eu = *(const unsigned*)&ecomb[(size_t)pr.x * KP + c];
    float e0 = __uint_as_float(eu << 16);
    float e1 = __uint_as_float(eu & 0xffff0000u);
    float e2 = 0.f, e3 = 0.f;
    if (tl) {
      unsigned x = *(const unsigned*)&ecomb[(size_t)pr.x * KP + c2];
      e2 = __uint_as_float(x << 16);
      e3 = __uint_as_float(x & 0xffff0000u);
    }
    unsigned ku = *(const unsigned*)&kbuf[(size_t)pr.y * 128 + c];
    unsigned vu = *(const unsigned*)&vbuf[(size_t)pr.y * 128 + c];
    float p = qv.x * __uint_as_float(ku << 16) + qv.y * __uint_as_float(ku & 0xffff0000u)
            + tx * e0 + ty * e1 + tx2 * e2 + ty2 * e3;
    #pragma unroll
    for (int off = 1; off < 64; off <<= 1) p += __shfl_xor(p, off, 64);
    att_upd(st, p * SC, vu, e0, e1, e2, e3);
  }
  int deg = end - beg;
  float inv = (deg > 0) ? 1.0f / (st.l * (float)deg) : 0.0f;
  float2 sk = *(const float2*)&accVS[(size_t)d * 128 + c];
  *(float2*)&accVS[(size_t)d * 128 + c] =
      make_float2(st.ax * inv + sk.x, st.ay * inv + sk.y);
  ushort2 oe; oe.x = f2bf(st.axe * inv); oe.y = f2bf(st.aye * inv);
  *(ushort2*)&accE[(size_t)d * KP + c] = oe;
  if (tl) {
    ushort2 oe2; oe2.x = f2bf(st.axe2 * inv); oe2.y = f2bf(st.aye2 * inv);
    *(ushort2*)&accE[(size_t)d * KP + c2] = oe2;
  }
}

extern "C" void kernel_launch(void* const* d_in, const int* in_sizes, int n_in,
                              void* d_out, int out_size, void* d_ws, size_t ws_size,
                              hipStream_t stream) {
  const float* var_learned = (const float*)d_in[0];
  const float* var_lp      = (const float*)d_in[1];
  const float* con_learned = (const float*)d_in[2];
  const float* con_lp      = (const float*)d_in[3];
  const float* edge_learned= (const float*)d_in[4];
  const float* lo          = (const float*)d_in[5];
  const float* hi          = (const float*)d_in[6];
  const float* dm          = (const float*)d_in[7];
  const float* wo          = (const float*)d_in[8];
  const float* cu_Wq = (const float*)d_in[9],  *cu_bq = (const float*)d_in[10];
  const float* cu_Wk = (const float*)d_in[11], *cu_bk = (const float*)d_in[12];
  const float* cu_Wv = (const float*)d_in[13], *cu_bv = (const float*)d_in[14];
  const float* cu_We = (const float*)d_in[15];
  const float* cu_Ws = (const float*)d_in[16], *cu_bs = (const float*)d_in[17];
  const float* vu_Wq = (const float*)d_in[18], *vu_bq = (const float*)d_in[19];
  const float* vu_Wk = (const float*)d_in[20], *vu_bk = (const float*)d_in[21];
  const float* vu_Wv = (const float*)d_in[22], *vu_bv = (const float*)d_in[23];
  const float* vu_We = (const float*)d_in[24];
  const float* vu_Ws = (const float*)d_in[25], *vu_bs = (const float*)d_in[26];
  const float* eu_vW1 = (const float*)d_in[27], *eu_vb1 = (const float*)d_in[28];
  const float* eu_vW2 = (const float*)d_in[29], *eu_vb2 = (const float*)d_in[30];
  const float* eu_cW1 = (const float*)d_in[31], *eu_cb1 = (const float*)d_in[32];
  const float* eu_cW2 = (const float*)d_in[33], *eu_cb2 = (const float*)d_in[34];
  const float* eu_eW1 = (const float*)d_in[35], *eu_eb1 = (const float*)d_in[36];
  const float* eu_eW2 = (const float*)d_in[37], *eu_eb2 = (const float*)d_in[38];
  const int* eiv = (const int*)d_in[39];
  const int* eic = (const int*)d_in[40];

  float* out_var  = (float*)d_out;
  float* out_con  = out_var + (size_t)NVV * 128;
  float* out_edge = out_con + (size_t)NCC * 128;

  // ---- workspace arena ----
  char* w = (char*)d_ws;
  auto alloc = [&](size_t bytes) { char* p = w; w += (bytes + 255) & ~(size_t)255; return p; };
  unsigned short* edge_comb_bf = (unsigned short*)alloc((size_t)NEE * KP * 2);  // 80MB
  unsigned short* var_comb_bf = (unsigned short*)alloc((size_t)NVV * KP * 2);
  unsigned short* con_comb_bf = (unsigned short*)alloc((size_t)NCC * KP * 2);
  unsigned short* t_bfA   = (unsigned short*)alloc((size_t)NCC * KP * 2);
  unsigned short* t_bfB   = (unsigned short*)alloc((size_t)NVV * KP * 2);
  unsigned short* accE_bf = (unsigned short*)alloc((size_t)NVV * KP * 2);
  unsigned short* kv_bf   = (unsigned short*)alloc((size_t)NVV * 128 * 2);
  unsigned short* vv_bf   = (unsigned short*)alloc((size_t)NVV * 128 * 2);
  unsigned short* vc_bf   = (unsigned short*)alloc((size_t)NVV * 128 * 2);
  unsigned short* cc_bf   = (unsigned short*)alloc((size_t)NCC * 128 * 2);
  float* bufV1 = (float*)alloc((size_t)NVV * 128 * 4);
  float* bufV2 = (float*)alloc((size_t)NVV * 128 * 4);
  float* bufC1 = (float*)alloc((size_t)NCC * 128 * 4);
  float* bufC2 = (float*)alloc((size_t)NCC * 128 * 4);
  unsigned short* WTbase = (unsigned short*)alloc((size_t)20 * 160 * KP * 2);
  int* countsC = (int*)alloc((size_t)NCC * 4);
  int* countsV = (int*)alloc((size_t)NVV * 4);
  int* offC = (int*)alloc((size_t)(NCC + 1) * 4);
  int* curC = (int*)alloc((size_t)NCC * 4);
  int* offV = (int*)alloc((size_t)(NVV + 1) * 4);
  int* curV = (int*)alloc((size_t)NVV * 4);
  int2* cesA = (int2*)alloc((size_t)NEE * 8);  // conv A (dst=con): {edge, src}
  int2* cesB = (int2*)alloc((size_t)NEE * 8);  // conv B (dst=var)
  (void)ws_size; (void)in_sizes; (void)n_in; (void)out_size;

  unsigned short* WT[20];
  for (int i = 0; i < 20; ++i) WT[i] = WTbase + (size_t)i * 160 * KP;
  WJobs jobs;
  const float* Wsrc[20] = {cu_Wq, cu_Wk, cu_Wv, cu_We, cu_Ws,
                           vu_Wq, vu_Wk, vu_Wv, vu_We, vu_Ws,
                           eu_vW1, eu_vW2, eu_cW1, eu_cW2,
                           eu_eW1, eu_eW1 + 136 * 128, eu_eW1 + 264 * 128, eu_eW2,
                           cu_We, vu_We};
  const int Ksrc[20] = {144, 144, 144, 136, 144, 144, 144, 144, 136, 144,
                        144, 128, 144, 128, 136, 128, 128, 128, 128, 128};
  const int Tsrc[20] = {1,1,1,1,1, 1,1,1,1,1, 1,1,1,1, 1,1,1,1, 0,0};
  for (int i = 0; i < 20; ++i) {
    jobs.W[i] = Wsrc[i]; jobs.O[i] = WT[i]; jobs.K[i] = Ksrc[i]; jobs.TR[i] = Tsrc[i];
  }

  const int T = 256;
  const int NBC = (NCC + 63) / 64;   // 196
  const int NBV = (NVV + 63) / 64;   // 391
  const int NBE2 = (NEE + 127) / 128; // 1954

  // ---- pre-passes ----
  build_node_bf<<<(NVV * 40 + T - 1) / T, T, 0, stream>>>(var_learned, var_lp, var_comb_bf, NVV);
  build_node_bf<<<(NCC * 40 + T - 1) / T, T, 0, stream>>>(con_learned, con_lp, con_comb_bf, NCC);
  build_edge_bf<<<(NEE * 40 + T - 1) / T, T, 0, stream>>>(edge_learned, lo, hi, dm, wo, edge_comb_bf);
  convert_weights<<<20 * 100, T, 0, stream>>>(jobs);

  // ---- CSR builds ----
  zero2<<<(NVV + T - 1) / T, T, 0, stream>>>(countsC, NCC, countsV, NVV);
  hist2<<<(NEE + T - 1) / T, T, 0, stream>>>(eic, countsC, eiv, countsV, NEE);
  csr_scan<<<1, 256, 0, stream>>>(countsC, offC, curC, NCC);
  csr_scan<<<1, 256, 0, stream>>>(countsV, offV, curV, NVV);
  csr_scatter<<<(NEE + T - 1) / T, T, 0, stream>>>(eic, eiv, curC, cesA, NEE);
  csr_scatter<<<(NEE + T - 1) / T, T, 0, stream>>>(eiv, eic, curV, cesB, NEE);

  // ---- q+t for BOTH convs in one dispatch (q_v reads ORIGINAL var_comb) ----
  {
    QTBatch b{};
    b.j[0] = {con_comb_bf, WT[0], cu_bq, WT[18], bufC1, t_bfA, NCC};
    b.j[1] = {var_comb_bf, WT[5], vu_bq, WT[19], bufV1, t_bfB, NVV};
    b.start = NBC;
    gemm_qt<<<NBC + NBV, 256, 0, stream>>>(b);
  }

  // ================= Stage A: con update (src=var, dst=con) =================
  {
    GBatch b{};
    b.j[0] = {con_comb_bf, WT[4], cu_bs, nullptr, bufC2, nullptr, 0, 0, NCC, 0, 0};   // skip_c
    b.j[1] = {var_comb_bf, WT[1], cu_bk, nullptr, nullptr, kv_bf, 128, 0, NVV, 0, 0}; // k_v
    b.j[2] = {var_comb_bf, WT[2], cu_bv, nullptr, nullptr, vv_bf, 128, 0, NVV, 0, 0}; // v_v
    b.start[0] = 0; b.start[1] = NBC; b.start[2] = NBC + NBV;
    b.njobs = 3;
    gemm_batch<<<NBC + 2 * NBV, 256, 0, stream>>>(b);
  }
  fused_attn<<<(NCC + 3) / 4, 256, 0, stream>>>(bufC1, kv_bf, vv_bf, t_bfA, edge_comb_bf,
                                                offC, cesA, bufC2, accE_bf, NCC);
  {
    GBatch b{};
    b.j[0] = {accE_bf, WT[3], nullptr, bufC2, out_con, con_comb_bf, KP, 0, NCC, 1, 1};
    b.start[0] = 0; b.njobs = 1;
    gemm_batch<<<NBC, 256, 0, stream>>>(b);    // con_new = relu(accE@We + accVS)
  }

  // ================= Stage B: var update (src=new con, dst=var) =================
  {
    GBatch b{};
    b.j[0] = {var_comb_bf, WT[9], vu_bs, nullptr, bufV2, nullptr, 0, 0, NVV, 0, 0};   // skip_v
    b.j[1] = {con_comb_bf, WT[6], vu_bk, nullptr, nullptr, kv_bf, 128, 0, NCC, 0, 0}; // k_c
    b.j[2] = {con_comb_bf, WT[7], vu_bv, nullptr, nullptr, vv_bf, 128, 0, NCC, 0, 0}; // v_c
    b.start[0] = 0; b.start[1] = NBV; b.start[2] = NBV + NBC;
    b.njobs = 3;
    gemm_batch<<<NBV + 2 * NBC, 256, 0, stream>>>(b);
  }
  fused_attn<<<(NVV + 3) / 4, 256, 0, stream>>>(bufV1, kv_bf, vv_bf, t_bfB, edge_comb_bf,
                                                offV, cesB, bufV2, accE_bf, NVV);
  {
    GBatch b{};
    b.j[0] = {accE_bf, WT[8], nullptr, bufV2, out_var, var_comb_bf, KP, 0, NVV, 1, 1};
    b.start[0] = 0; b.njobs = 1;
    gemm_batch<<<NBV, 256, 0, stream>>>(b);    // var_new = relu(accE@We + accVS)
  }

  // ================= Edge stage =================
  gemm_chain<<<NBV, 256, 0, stream>>>(
      var_comb_bf, WT[10], eu_vb1, WT[11], eu_vb2, WT[15], vc_bf, NVV);   // vcW (bf16)
  gemm_chain<<<NBC, 256, 0, stream>>>(
      con_comb_bf, WT[12], eu_cb1, WT[13], eu_cb2, WT[16], cc_bf, NCC);   // ccW (bf16)
  gemm_edge2<<<NBE2, 256, 0, stream>>>(
      edge_comb_bf, WT[14], eu_eb1, vc_bf, cc_bf, eiv, eic,
      WT[17], eu_eb2, out_edge, NEE);                                      // edge_new
}

// Round 8
// 741.367 us; speedup vs baseline: 1.2685x; 1.0458x over previous
//
#include <hip/hip_runtime.h>
#include <math.h>

#define NVV 25000
#define NCC 12500
#define NEE 250000
#define KP 160   // padded K for all bf16 GEMM inputs (covers K=128,136,144)

typedef short bf16x8 __attribute__((ext_vector_type(8)));
typedef float f32x4 __attribute__((ext_vector_type(4)));

// ---------- helpers ----------
__device__ __forceinline__ unsigned short f2bf(float f) {  // RNE fp32->bf16
  unsigned u = __float_as_uint(f);
  u += 0x7fffu + ((u >> 16) & 1u);
  return (unsigned short)(u >> 16);
}
__device__ __forceinline__ float bf2f(unsigned short u) {
  return __uint_as_float((unsigned)u << 16);
}
__device__ __forceinline__ void gll16(const unsigned short* g, unsigned short* l) {
  __builtin_amdgcn_global_load_lds(
      (const __attribute__((address_space(1))) unsigned int*)(const void*)g,
      (__attribute__((address_space(3))) unsigned int*)(void*)l, 16, 0, 0);
}

// Stage a 64-row x 160-k bf16 strip (20KB) into LDS chunk layout [kk][row64][32].
__device__ __forceinline__ void stage_rows64(const unsigned short* __restrict__ X,
                                             unsigned short* As, int row0, int N,
                                             int wave, int lane) {
  #pragma unroll
  for (int j = 0; j < 5; ++j) {
    int inst = wave * 5 + j;                 // 0..19
    int L = inst * 1024 + lane * 16;         // byte offset in As
    int kk = L >> 12;                        // 4096B per chunk (64 rows x 64B)
    int r = (L >> 6) & 63;
    int ks = (L & 63) >> 1;
    int grow = row0 + r; if (grow >= N) grow = N - 1;
    gll16(X + (size_t)grow * KP + kk * 32 + ks, As + inst * 512);
  }
}

template <int MI, int NI>
__device__ __forceinline__ void zero_acc(f32x4 (&acc)[MI][NI]) {
  #pragma unroll
  for (int mi = 0; mi < MI; ++mi)
    #pragma unroll
    for (int ni = 0; ni < NI; ++ni) {
      acc[mi][ni][0] = 0.f; acc[mi][ni][1] = 0.f;
      acc[mi][ni][2] = 0.f; acc[mi][ni][3] = 0.f;
    }
}

// One K-chunk (32) of MFMA: A fragments from LDS, B fragments from global
// (weights are a 40KB L2-hot table shared by all blocks).
template <int MI, int NI>
__device__ __forceinline__ void chunk_mfma_g(const unsigned short* As,
                                             const unsigned short* __restrict__ WT,
                                             f32x4 (&acc)[MI][NI], int kk,
                                             int wm, int wn, int fr, int fq) {
  bf16x8 av[MI], bv[NI];
  #pragma unroll
  for (int mi = 0; mi < MI; ++mi)
    av[mi] = *(const bf16x8*)&As[kk * 2048 + (wm + mi * 16 + fr) * 32 + fq * 8];
  #pragma unroll
  for (int ni = 0; ni < NI; ++ni)
    bv[ni] = *(const bf16x8*)&WT[(size_t)(wn + ni * 16 + fr) * KP + kk * 32 + fq * 8];
  #pragma unroll
  for (int mi = 0; mi < MI; ++mi)
    #pragma unroll
    for (int ni = 0; ni < NI; ++ni)
      acc[mi][ni] = __builtin_amdgcn_mfma_f32_16x16x32_bf16(av[mi], bv[ni],
                                                            acc[mi][ni], 0, 0, 0);
}

// init acc with bias (uniform per col)
__device__ __forceinline__ void init_bias(f32x4 (&acc)[2][4], const float* __restrict__ b,
                                          int wn, int fr) {
  #pragma unroll
  for (int ni = 0; ni < 4; ++ni) {
    float bvv = b[wn + ni * 16 + fr];
    #pragma unroll
    for (int mi = 0; mi < 2; ++mi) {
      acc[mi][ni][0] = bvv; acc[mi][ni][1] = bvv;
      acc[mi][ni][2] = bvv; acc[mi][ni][3] = bvv;
    }
  }
}

// ---------- unified single-stage(+optional t) GEMM, batched ----------
// out[N,128] = X[N,160] @ W1^T + b1 ; optional second stage t = out@Wt (NI=5)
struct MJob {
  const unsigned short* X; const unsigned short* W1; const float* b1;
  const unsigned short* Wt;      // if non-null: second stage -> tb (KP stride)
  float* outf; unsigned short* outb; unsigned short* tb;
  int N;
};
struct MBatch { MJob j[6]; int start[6]; int njobs; };

__global__ __launch_bounds__(256, 4) void gemm_multi(MBatch B) {
  int job = 0;
  #pragma unroll
  for (int t = 1; t < 6; ++t)
    if (t < B.njobs && (int)blockIdx.x >= B.start[t]) job = t;
  MJob g = B.j[job];
  __shared__ unsigned short As[5 * 64 * 32];   // 20 KB
  const int tid = threadIdx.x;
  const int lane = tid & 63, wave = tid >> 6;
  const int row0 = (blockIdx.x - B.start[job]) * 64;
  const int wm = (wave & 1) * 32;
  const int fr = lane & 15, fq = lane >> 4;

  stage_rows64(g.X, As, row0, g.N, wave, lane);
  const int wn = (wave >> 1) * 64;
  f32x4 acc[2][4];
  init_bias(acc, g.b1, wn, fr);
  __syncthreads();
  #pragma unroll
  for (int kk = 0; kk < 5; ++kk) chunk_mfma_g<2, 4>(As, g.W1, acc, kk, wm, wn, fr, fq);

  if (!g.Wt) {
    #pragma unroll
    for (int mi = 0; mi < 2; ++mi)
      #pragma unroll
      for (int ni = 0; ni < 4; ++ni) {
        int gcol = wn + ni * 16 + fr;
        #pragma unroll
        for (int r = 0; r < 4; ++r) {
          int grow = row0 + wm + mi * 16 + fq * 4 + r;
          if (grow < g.N) {
            float o = acc[mi][ni][r];
            if (g.outf) g.outf[(size_t)grow * 128 + gcol] = o;
            if (g.outb) g.outb[(size_t)grow * 128 + gcol] = f2bf(o);
          }
        }
      }
  } else {
    __syncthreads();                   // stage-1 LDS reads done
    #pragma unroll
    for (int mi = 0; mi < 2; ++mi)
      #pragma unroll
      for (int ni = 0; ni < 4; ++ni) {
        int col = wn + ni * 16 + fr;
        #pragma unroll
        for (int r = 0; r < 4; ++r) {
          int row = wm + mi * 16 + fq * 4 + r;
          int grow = row0 + row;
          float o = acc[mi][ni][r];
          if (grow < g.N) g.outf[(size_t)grow * 128 + col] = o;
          As[(col >> 5) * 2048 + row * 32 + (col & 31)] = f2bf(o);
        }
      }
    __syncthreads();                   // T2 visible
    const int wn5 = (wave >> 1) * 80;  // NI=5 layout
    f32x4 acc2[2][5];
    zero_acc<2, 5>(acc2);
    #pragma unroll
    for (int kk = 0; kk < 4; ++kk) chunk_mfma_g<2, 5>(As, g.Wt, acc2, kk, wm, wn5, fr, fq);
    #pragma unroll
    for (int mi = 0; mi < 2; ++mi)
      #pragma unroll
      for (int ni = 0; ni < 5; ++ni) {
        int gcol = wn5 + ni * 16 + fr;
        #pragma unroll
        for (int r = 0; r < 4; ++r) {
          int grow = row0 + wm + mi * 16 + fq * 4 + r;
          if (grow < g.N) g.tb[(size_t)grow * KP + gcol] = f2bf(acc2[mi][ni][r]);
        }
      }
  }
}

// ---------- node_update: new node features + dependent projections ----------
// stage1: newf = relu(accE@We + accVS) -> outF (f32 NT); T2' = [newf|lp] in LDS
// then (optional) k = T2'@Wk+bk, v = T2'@Wv+bv; then 3-stage chain -> cout.
__global__ __launch_bounds__(256, 4) void node_update(
    const unsigned short* __restrict__ accE, const float* __restrict__ accVS,
    const float* __restrict__ lp,
    const unsigned short* __restrict__ We, float* __restrict__ outF,
    const unsigned short* __restrict__ Wk, const float* __restrict__ bk,
    unsigned short* __restrict__ kout,
    const unsigned short* __restrict__ Wv, const float* __restrict__ bv,
    unsigned short* __restrict__ vout,
    const unsigned short* __restrict__ C1, const float* __restrict__ c1b,
    const unsigned short* __restrict__ C2, const float* __restrict__ c2b,
    const unsigned short* __restrict__ C3, unsigned short* __restrict__ cout,
    int N) {
  __shared__ unsigned short As[5 * 64 * 32];   // 20 KB
  const int tid = threadIdx.x;
  const int lane = tid & 63, wave = tid >> 6;
  const int row0 = blockIdx.x * 64;
  const int wm = (wave & 1) * 32, wn = (wave >> 1) * 64;
  const int fr = lane & 15, fq = lane >> 4;

  // lp prefetch (thread t -> row t>>2, cols (t&3)*4..+3)
  int lrow = row0 + (tid >> 2); if (lrow >= N) lrow = N - 1;
  float4 lpv = *(const float4*)&lp[(size_t)lrow * 16 + (tid & 3) * 4];

  stage_rows64(accE, As, row0, N, wave, lane);

  f32x4 acc[2][4];
  // init acc from accVS (skip+attn aggregate); loads hide under staging
  #pragma unroll
  for (int mi = 0; mi < 2; ++mi)
    #pragma unroll
    for (int ni = 0; ni < 4; ++ni) {
      int col = wn + ni * 16 + fr;
      #pragma unroll
      for (int r = 0; r < 4; ++r) {
        int grow = row0 + wm + mi * 16 + fq * 4 + r;
        int gi = (grow < N) ? grow : (N - 1);
        acc[mi][ni][r] = accVS[(size_t)gi * 128 + col];
      }
    }
  __syncthreads();
  #pragma unroll
  for (int kk = 0; kk < 5; ++kk) chunk_mfma_g<2, 4>(As, We, acc, kk, wm, wn, fr, fq);
  __syncthreads();                       // stage-1 As reads done

  // epi1: relu -> outF + T2' chunks 0-3
  #pragma unroll
  for (int mi = 0; mi < 2; ++mi)
    #pragma unroll
    for (int ni = 0; ni < 4; ++ni) {
      int col = wn + ni * 16 + fr;
      #pragma unroll
      for (int r = 0; r < 4; ++r) {
        int row = wm + mi * 16 + fq * 4 + r;
        int grow = row0 + row;
        float o = fmaxf(acc[mi][ni][r], 0.f);
        if (grow < N) __builtin_nontemporal_store(o, &outF[(size_t)grow * 128 + col]);
        As[(col >> 5) * 2048 + row * 32 + (col & 31)] = f2bf(o);
      }
    }
  // lp -> chunk 4 cols 0..15 (cols 128..143); cols 144+ stay zero (accE pad)
  {
    int r = tid >> 2, cb = (tid & 3) * 4;
    unsigned short* p = &As[4 * 2048 + r * 32 + cb];
    p[0] = f2bf(lpv.x); p[1] = f2bf(lpv.y); p[2] = f2bf(lpv.z); p[3] = f2bf(lpv.w);
  }
  __syncthreads();                       // T2' visible

  if (Wk) {
    init_bias(acc, bk, wn, fr);
    #pragma unroll
    for (int kk = 0; kk < 5; ++kk) chunk_mfma_g<2, 4>(As, Wk, acc, kk, wm, wn, fr, fq);
    #pragma unroll
    for (int mi = 0; mi < 2; ++mi)
      #pragma unroll
      for (int ni = 0; ni < 4; ++ni) {
        int gcol = wn + ni * 16 + fr;
        #pragma unroll
        for (int r = 0; r < 4; ++r) {
          int grow = row0 + wm + mi * 16 + fq * 4 + r;
          if (grow < N) kout[(size_t)grow * 128 + gcol] = f2bf(acc[mi][ni][r]);
        }
      }
    init_bias(acc, bv, wn, fr);
    #pragma unroll
    for (int kk = 0; kk < 5; ++kk) chunk_mfma_g<2, 4>(As, Wv, acc, kk, wm, wn, fr, fq);
    #pragma unroll
    for (int mi = 0; mi < 2; ++mi)
      #pragma unroll
      for (int ni = 0; ni < 4; ++ni) {
        int gcol = wn + ni * 16 + fr;
        #pragma unroll
        for (int r = 0; r < 4; ++r) {
          int grow = row0 + wm + mi * 16 + fq * 4 + r;
          if (grow < N) vout[(size_t)grow * 128 + gcol] = f2bf(acc[mi][ni][r]);
        }
      }
  }

  // compress chain: T2'@C1+c1b relu -> @C2+c2b relu -> @C3 -> cout
  init_bias(acc, c1b, wn, fr);
  #pragma unroll
  for (int kk = 0; kk < 5; ++kk) chunk_mfma_g<2, 4>(As, C1, acc, kk, wm, wn, fr, fq);
  __syncthreads();
  #pragma unroll
  for (int mi = 0; mi < 2; ++mi)
    #pragma unroll
    for (int ni = 0; ni < 4; ++ni) {
      int col = wn + ni * 16 + fr;
      #pragma unroll
      for (int r = 0; r < 4; ++r) {
        int row = wm + mi * 16 + fq * 4 + r;
        float o = fmaxf(acc[mi][ni][r], 0.f);
        As[(col >> 5) * 2048 + row * 32 + (col & 31)] = f2bf(o);
      }
    }
  __syncthreads();
  init_bias(acc, c2b, wn, fr);
  #pragma unroll
  for (int kk = 0; kk < 4; ++kk) chunk_mfma_g<2, 4>(As, C2, acc, kk, wm, wn, fr, fq);
  __syncthreads();
  #pragma unroll
  for (int mi = 0; mi < 2; ++mi)
    #pragma unroll
    for (int ni = 0; ni < 4; ++ni) {
      int col = wn + ni * 16 + fr;
      #pragma unroll
      for (int r = 0; r < 4; ++r) {
        int row = wm + mi * 16 + fq * 4 + r;
        float o = fmaxf(acc[mi][ni][r], 0.f);
        As[(col >> 5) * 2048 + row * 32 + (col & 31)] = f2bf(o);
      }
    }
  __syncthreads();
  zero_acc<2, 4>(acc);
  #pragma unroll
  for (int kk = 0; kk < 4; ++kk) chunk_mfma_g<2, 4>(As, C3, acc, kk, wm, wn, fr, fq);
  #pragma unroll
  for (int mi = 0; mi < 2; ++mi)
    #pragma unroll
    for (int ni = 0; ni < 4; ++ni) {
      int gcol = wn + ni * 16 + fr;
      #pragma unroll
      for (int r = 0; r < 4; ++r) {
        int grow = row0 + wm + mi * 16 + fq * 4 + r;
        if (grow < N) cout[(size_t)grow * 128 + gcol] = f2bf(acc[mi][ni][r]);
      }
    }
}

// ---------- edge kernel: 2-tile pipelined, 2-stage chained ----------
// acc initialized to b1 + gathered vcW/ccW rows BEFORE the staging barrier,
// so the scattered gather loads complete under the 40KB staging wait.
__device__ __forceinline__ void init_gather(f32x4 (&acc)[2][4], int rbase, int N,
    const float* __restrict__ b1,
    const unsigned short* __restrict__ gA, const unsigned short* __restrict__ gB,
    const int* __restrict__ giA, const int* __restrict__ giB,
    int wm, int wn, int fr, int fq) {
  #pragma unroll
  for (int mi = 0; mi < 2; ++mi)
    #pragma unroll
    for (int ni = 0; ni < 4; ++ni) {
      int col = wn + ni * 16 + fr;
      float bvv = b1[col];
      #pragma unroll
      for (int r = 0; r < 4; ++r) {
        int grow = rbase + wm + mi * 16 + fq * 4 + r;
        int gi = (grow < N) ? grow : (N - 1);
        acc[mi][ni][r] = bvv + bf2f(gA[(size_t)giA[gi] * 128 + col])
                             + bf2f(gB[(size_t)giB[gi] * 128 + col]);
      }
    }
}
__device__ __forceinline__ void epi_relu_lds(unsigned short* L, const f32x4 (&acc)[2][4],
    int wm, int wn, int fr, int fq) {
  #pragma unroll
  for (int mi = 0; mi < 2; ++mi)
    #pragma unroll
    for (int ni = 0; ni < 4; ++ni) {
      int col = wn + ni * 16 + fr;
      #pragma unroll
      for (int r = 0; r < 4; ++r) {
        int row = wm + mi * 16 + fq * 4 + r;
        float o = fmaxf(acc[mi][ni][r], 0.f);
        L[(col >> 5) * 2048 + row * 32 + (col & 31)] = f2bf(o);
      }
    }
}
__device__ __forceinline__ void edge_store(const f32x4 (&acc)[2][4], int rbase, int N,
    const float* __restrict__ b2, float* __restrict__ outf,
    int wm, int wn, int fr, int fq) {
  #pragma unroll
  for (int mi = 0; mi < 2; ++mi)
    #pragma unroll
    for (int ni = 0; ni < 4; ++ni) {
      int gcol = wn + ni * 16 + fr;
      float bvv = b2[gcol];
      #pragma unroll
      for (int r = 0; r < 4; ++r) {
        int grow = rbase + wm + mi * 16 + fq * 4 + r;
        if (grow < N) {
          float o = fmaxf(acc[mi][ni][r] + bvv, 0.f);
          __builtin_nontemporal_store(o, &outf[(size_t)grow * 128 + gcol]);
        }
      }
    }
}

__global__ __launch_bounds__(256, 4) void gemm_edge2(
    const unsigned short* __restrict__ X,
    const unsigned short* __restrict__ W1, const float* __restrict__ b1,
    const unsigned short* __restrict__ gA, const unsigned short* __restrict__ gB,
    const int* __restrict__ giA, const int* __restrict__ giB,
    const unsigned short* __restrict__ W2, const float* __restrict__ b2,
    float* __restrict__ outf, int N) {
  __shared__ unsigned short As[5 * 64 * 32];   // tile A (20 KB)
  __shared__ unsigned short Bs[5 * 64 * 32];   // tile B (20 KB)
  const int tid = threadIdx.x;
  const int lane = tid & 63, wave = tid >> 6;
  const int row0 = blockIdx.x * 128;
  const int wm = (wave & 1) * 32, wn = (wave >> 1) * 64;
  const int fr = lane & 15, fq = lane >> 4;

  stage_rows64(X, As, row0, N, wave, lane);
  f32x4 acc[2][4];
  init_gather(acc, row0, N, b1, gA, gB, giA, giB, wm, wn, fr, fq);
  __syncthreads();                               // A + gathers resident
  stage_rows64(X, Bs, row0 + 64, N, wave, lane); // B latency hides under A's work

  // ---- tile A ----
  #pragma unroll
  for (int kk = 0; kk < 5; ++kk) chunk_mfma_g<2, 4>(As, W1, acc, kk, wm, wn, fr, fq);
  __syncthreads();                               // A reads done; B resident too
  epi_relu_lds(As, acc, wm, wn, fr, fq);
  zero_acc<2, 4>(acc);
  __syncthreads();
  #pragma unroll
  for (int kk = 0; kk < 4; ++kk) chunk_mfma_g<2, 4>(As, W2, acc, kk, wm, wn, fr, fq);
  edge_store(acc, row0, N, b2, outf, wm, wn, fr, fq);

  // ---- tile B ----
  init_gather(acc, row0 + 64, N, b1, gA, gB, giA, giB, wm, wn, fr, fq);
  #pragma unroll
  for (int kk = 0; kk < 5; ++kk) chunk_mfma_g<2, 4>(Bs, W1, acc, kk, wm, wn, fr, fq);
  __syncthreads();
  epi_relu_lds(Bs, acc, wm, wn, fr, fq);
  zero_acc<2, 4>(acc);
  __syncthreads();
  #pragma unroll
  for (int kk = 0; kk < 4; ++kk) chunk_mfma_g<2, 4>(Bs, W2, acc, kk, wm, wn, fr, fq);
  edge_store(acc, row0 + 64, N, b2, outf, wm, wn, fr, fq);
}

// ---------- build bf16 combined features ----------
__global__ void build_node_bf(const float* __restrict__ learned, const float* __restrict__ lp,
                              unsigned short* __restrict__ out, int N) {
  int idx = blockIdx.x * blockDim.x + threadIdx.x;
  if (idx >= N * 40) return;
  int row = idx / 40, c4 = idx - row * 40;
  int c = c4 * 4;
  ushort4 o;
  if (c4 < 32) {
    const float* p = learned + (size_t)row * 128 + c;
    o.x = f2bf(p[0]); o.y = f2bf(p[1]); o.z = f2bf(p[2]); o.w = f2bf(p[3]);
  } else if (c4 < 36) {
    const float* p = lp + (size_t)row * 16 + (c - 128);
    o.x = f2bf(p[0]); o.y = f2bf(p[1]); o.z = f2bf(p[2]); o.w = f2bf(p[3]);
  } else { o.x = o.y = o.z = o.w = 0; }
  *(ushort4*)&out[(size_t)row * KP + c] = o;
}

__global__ void build_edge_bf(const float* __restrict__ el, const float* __restrict__ lo,
                              const float* __restrict__ hi, const float* __restrict__ dm,
                              const float* __restrict__ wo, unsigned short* __restrict__ out) {
  int idx = blockIdx.x * blockDim.x + threadIdx.x;
  if (idx >= NEE * 40) return;
  int row = idx / 40, c4 = idx - row * 40;
  int c = c4 * 4;
  ushort4 o;
  if (c4 < 32) {
    const float* p = el + (size_t)row * 128 + c;
    o.x = f2bf(p[0]); o.y = f2bf(p[1]); o.z = f2bf(p[2]); o.w = f2bf(p[3]);
  } else if (c4 == 32) {
    o.x = f2bf(lo[row]); o.y = f2bf(hi[row]); o.z = f2bf(dm[row]);
    o.w = f2bf(wo[(size_t)row * 5 + 0]);
  } else if (c4 == 33) {
    const float* p = wo + (size_t)row * 5;
    o.x = f2bf(p[1]); o.y = f2bf(p[2]); o.z = f2bf(p[3]); o.w = f2bf(p[4]);
  } else { o.x = o.y = o.z = o.w = 0; }
  *(ushort4*)&out[(size_t)row * KP + c] = o;
}

// ---------- weight transpose/copy + convert ----------
struct WJobs {
  const float* W[20];
  unsigned short* O[20];
  int K[20];
  int TR[20];
};
__global__ void convert_weights(WJobs j) {
  int b = blockIdx.x;
  int job = b / 100;
  int i = (b - job * 100) * 256 + threadIdx.x;   // 0 .. 160*KP
  int col = i / KP;
  int k = i - col * KP;
  float v = 0.f;
  if (j.TR[job]) { if (col < 128 && k < j.K[job]) v = j.W[job][(size_t)k * 128 + col]; }
  else           { if (col < 136 && k < j.K[job]) v = j.W[job][(size_t)col * 128 + k]; }
  j.O[job][(size_t)col * KP + k] = f2bf(v);
}

// ---------- CSR construction ----------
__global__ void zero2(int* __restrict__ a, int na, int* __restrict__ b, int nb) {
  int i = blockIdx.x * blockDim.x + threadIdx.x;
  if (i < na) a[i] = 0;
  if (i < nb) b[i] = 0;
}
__global__ void hist2(const int* __restrict__ dc, int* __restrict__ cc,
                      const int* __restrict__ dv, int* __restrict__ cv, int nE) {
  int e = blockIdx.x * blockDim.x + threadIdx.x;
  if (e >= nE) return;
  atomicAdd(&cc[dc[e]], 1);
  atomicAdd(&cv[dv[e]], 1);
}
__global__ void csr_scan(const int* __restrict__ counts, int* __restrict__ offsets,
                         int* __restrict__ cursor, int n) {
  __shared__ int part[256];
  int tid = threadIdx.x;
  int chunk = (n + 255) / 256;
  int lo = tid * chunk, hi = min(n, lo + chunk);
  int s = 0;
  for (int i = lo; i < hi; ++i) s += counts[i];
  part[tid] = s;
  __syncthreads();
  if (tid == 0) {
    int run = 0;
    for (int i = 0; i < 256; ++i) { int t = part[i]; part[i] = run; run += t; }
    offsets[n] = run;
  }
  __syncthreads();
  int base = part[tid];
  for (int i = lo; i < hi; ++i) { offsets[i] = base; cursor[i] = base; base += counts[i]; }
}
__global__ void csr_scatter(const int* __restrict__ dst, const int* __restrict__ src,
                            int* __restrict__ cursor, int2* __restrict__ ces, int nE) {
  int e = blockIdx.x * blockDim.x + threadIdx.x;
  if (e >= nE) return;
  int pos = atomicAdd(&cursor[dst[e]], 1);
  ces[pos] = make_int2(e, src[e]);
}

// ---------- fused flash-style segment attention: one wave per dst ----------
struct AttSt { float m, l, ax, ay, axe, aye, axe2, aye2; };
__device__ __forceinline__ void att_upd(AttSt& s, float alpha, unsigned vu,
                                        float e0, float e1, float e2, float e3) {
  float mn = fmaxf(s.m, alpha);
  float scale = __expf(s.m - mn);
  float w = __expf(alpha - mn);
  s.ax = s.ax * scale + __uint_as_float(vu << 16) * w;
  s.ay = s.ay * scale + __uint_as_float(vu & 0xffff0000u) * w;
  s.axe = s.axe * scale + e0 * w;   s.aye = s.aye * scale + e1 * w;
  s.axe2 = s.axe2 * scale + e2 * w; s.aye2 = s.aye2 * scale + e3 * w;
  s.l = s.l * scale + w; s.m = mn;
}

__global__ void fused_attn(
    const float* __restrict__ qbuf, const unsigned short* __restrict__ kbuf,
    const unsigned short* __restrict__ vbuf, const unsigned short* __restrict__ tbuf,
    const unsigned short* __restrict__ ecomb,
    const int* __restrict__ offsets, const int2* __restrict__ ces,
    float* __restrict__ accVS, unsigned short* __restrict__ accE, int Nd) {
  int d = blockIdx.x * 4 + (threadIdx.x >> 6);
  if (d >= Nd) return;
  int lane = threadIdx.x & 63;
  int c = lane * 2;
  bool tl = (lane < 16);
  int c2 = 128 + c;
  float2 qv = *(const float2*)&qbuf[(size_t)d * 128 + c];
  unsigned tu = *(const unsigned*)&tbuf[(size_t)d * KP + c];
  float tx = __uint_as_float(tu << 16);
  float ty = __uint_as_float(tu & 0xffff0000u);
  float tx2 = 0.f, ty2 = 0.f;
  if (tl) {
    unsigned tu2 = *(const unsigned*)&tbuf[(size_t)d * KP + c2];
    tx2 = __uint_as_float(tu2 << 16);
    ty2 = __uint_as_float(tu2 & 0xffff0000u);
  }
  int beg = offsets[d], end = offsets[d + 1];
  AttSt st{-INFINITY, 0.f, 0.f, 0.f, 0.f, 0.f, 0.f, 0.f};
  const float SC = 0.08838834764831845f;  // 1/sqrt(128)
  int i = beg;
  for (; i + 3 < end; i += 4) {
    int2 pr[4];
    pr[0] = ces[i]; pr[1] = ces[i + 1]; pr[2] = ces[i + 2]; pr[3] = ces[i + 3];
    unsigned eu[4], ku[4], vu[4];
    float e0[4], e1[4], e2[4], e3[4], p[4];
    #pragma unroll
    for (int u = 0; u < 4; ++u) {
      eu[u] = *(const unsigned*)&ecomb[(size_t)pr[u].x * KP + c];
      ku[u] = *(const unsigned*)&kbuf[(size_t)pr[u].y * 128 + c];
      vu[u] = *(const unsigned*)&vbuf[(size_t)pr[u].y * 128 + c];
    }
    #pragma unroll
    for (int u = 0; u < 4; ++u) {
      e0[u] = __uint_as_float(eu[u] << 16);
      e1[u] = __uint_as_float(eu[u] & 0xffff0000u);
      e2[u] = 0.f; e3[u] = 0.f;
    }
    if (tl) {
      #pragma unroll
      for (int u = 0; u < 4; ++u) {
        unsigned x = *(const unsigned*)&ecomb[(size_t)pr[u].x * KP + c2];
        e2[u] = __uint_as_float(x << 16);
        e3[u] = __uint_as_float(x & 0xffff0000u);
      }
    }
    #pragma unroll
    for (int u = 0; u < 4; ++u)
      p[u] = qv.x * __uint_as_float(ku[u] << 16) + qv.y * __uint_as_float(ku[u] & 0xffff0000u)
           + tx * e0[u] + ty * e1[u] + tx2 * e2[u] + ty2 * e3[u];
    #pragma unroll
    for (int off = 1; off < 64; off <<= 1) {
      p[0] += __shfl_xor(p[0], off, 64);
      p[1] += __shfl_xor(p[1], off, 64);
      p[2] += __shfl_xor(p[2], off, 64);
      p[3] += __shfl_xor(p[3], off, 64);
    }
    #pragma unroll
    for (int u = 0; u < 4; ++u)
      att_upd(st, p[u] * SC, vu[u], e0[u], e1[u], e2[u], e3[u]);
  }
  for (; i < end; ++i) {
    int2 pr = ces[i];
    unsigned eu = *(const unsigned*)&ecomb[(size_t)pr.x * KP + c];
    float e0 = __uint_as_float(eu << 16);
    float e1 = __uint_as_float(eu & 0xffff0000u);
    float e2 = 0.f, e3 = 0.f;
    if (tl) {
      unsigned x = *(const unsigned*)&ecomb[(size_t)pr.x * KP + c2];
      e2 = __uint_as_float(x << 16);
      e3 = __uint_as_float(x & 0xffff0000u);
    }
    unsigned ku = *(const unsigned*)&kbuf[(size_t)pr.y * 128 + c];
    unsigned vu = *(const unsigned*)&vbuf[(size_t)pr.y * 128 + c];
    float p = qv.x * __uint_as_float(ku << 16) + qv.y * __uint_as_float(ku & 0xffff0000u)
            + tx * e0 + ty * e1 + tx2 * e2 + ty2 * e3;
    #pragma unroll
    for (int off = 1; off < 64; off <<= 1) p += __shfl_xor(p, off, 64);
    att_upd(st, p * SC, vu, e0, e1, e2, e3);
  }
  int deg = end - beg;
  float inv = (deg > 0) ? 1.0f / (st.l * (float)deg) : 0.0f;
  float2 sk = *(const float2*)&accVS[(size_t)d * 128 + c];
  *(float2*)&accVS[(size_t)d * 128 + c] =
      make_float2(st.ax * inv + sk.x, st.ay * inv + sk.y);
  ushort2 oe; oe.x = f2bf(st.axe * inv); oe.y = f2bf(st.aye * inv);
  *(ushort2*)&accE[(size_t)d * KP + c] = oe;
  if (tl) {
    ushort2 oe2; oe2.x = f2bf(st.axe2 * inv); oe2.y = f2bf(st.aye2 * inv);
    *(ushort2*)&accE[(size_t)d * KP + c2] = oe2;
  }
}

extern "C" void kernel_launch(void* const* d_in, const int* in_sizes, int n_in,
                              void* d_out, int out_size, void* d_ws, size_t ws_size,
                              hipStream_t stream) {
  const float* var_learned = (const float*)d_in[0];
  const float* var_lp      = (const float*)d_in[1];
  const float* con_learned = (const float*)d_in[2];
  const float* con_lp      = (const float*)d_in[3];
  const float* edge_learned= (const float*)d_in[4];
  const float* lo          = (const float*)d_in[5];
  const float* hi          = (const float*)d_in[6];
  const float* dm          = (const float*)d_in[7];
  const float* wo          = (const float*)d_in[8];
  const float* cu_Wq = (const float*)d_in[9],  *cu_bq = (const float*)d_in[10];
  const float* cu_Wk = (const float*)d_in[11], *cu_bk = (const float*)d_in[12];
  const float* cu_Wv = (const float*)d_in[13], *cu_bv = (const float*)d_in[14];
  const float* cu_We = (const float*)d_in[15];
  const float* cu_Ws = (const float*)d_in[16], *cu_bs = (const float*)d_in[17];
  const float* vu_Wq = (const float*)d_in[18], *vu_bq = (const float*)d_in[19];
  const float* vu_Wk = (const float*)d_in[20], *vu_bk = (const float*)d_in[21];
  const float* vu_Wv = (const float*)d_in[22], *vu_bv = (const float*)d_in[23];
  const float* vu_We = (const float*)d_in[24];
  const float* vu_Ws = (const float*)d_in[25], *vu_bs = (const float*)d_in[26];
  const float* eu_vW1 = (const float*)d_in[27], *eu_vb1 = (const float*)d_in[28];
  const float* eu_vW2 = (const float*)d_in[29], *eu_vb2 = (const float*)d_in[30];
  const float* eu_cW1 = (const float*)d_in[31], *eu_cb1 = (const float*)d_in[32];
  const float* eu_cW2 = (const float*)d_in[33], *eu_cb2 = (const float*)d_in[34];
  const float* eu_eW1 = (const float*)d_in[35], *eu_eb1 = (const float*)d_in[36];
  const float* eu_eW2 = (const float*)d_in[37], *eu_eb2 = (const float*)d_in[38];
  const int* eiv = (const int*)d_in[39];
  const int* eic = (const int*)d_in[40];

  float* out_var  = (float*)d_out;
  float* out_con  = out_var + (size_t)NVV * 128;
  float* out_edge = out_con + (size_t)NCC * 128;

  // ---- workspace arena ----
  char* w = (char*)d_ws;
  auto alloc = [&](size_t bytes) { char* p = w; w += (bytes + 255) & ~(size_t)255; return p; };
  unsigned short* edge_comb_bf = (unsigned short*)alloc((size_t)NEE * KP * 2);  // 80MB
  unsigned short* var_comb_bf = (unsigned short*)alloc((size_t)NVV * KP * 2);
  unsigned short* con_comb_bf = (unsigned short*)alloc((size_t)NCC * KP * 2);
  unsigned short* t_bfA   = (unsigned short*)alloc((size_t)NCC * KP * 2);
  unsigned short* t_bfB   = (unsigned short*)alloc((size_t)NVV * KP * 2);
  unsigned short* accE_bf = (unsigned short*)alloc((size_t)NVV * KP * 2);
  unsigned short* kv_bf   = (unsigned short*)alloc((size_t)NVV * 128 * 2);
  unsigned short* vv_bf   = (unsigned short*)alloc((size_t)NVV * 128 * 2);
  unsigned short* vc_bf   = (unsigned short*)alloc((size_t)NVV * 128 * 2);
  unsigned short* cc_bf   = (unsigned short*)alloc((size_t)NCC * 128 * 2);
  float* bufV1 = (float*)alloc((size_t)NVV * 128 * 4);
  float* bufV2 = (float*)alloc((size_t)NVV * 128 * 4);
  float* bufC1 = (float*)alloc((size_t)NCC * 128 * 4);
  float* bufC2 = (float*)alloc((size_t)NCC * 128 * 4);
  unsigned short* WTbase = (unsigned short*)alloc((size_t)20 * 160 * KP * 2);
  int* countsC = (int*)alloc((size_t)NCC * 4);
  int* countsV = (int*)alloc((size_t)NVV * 4);
  int* offC = (int*)alloc((size_t)(NCC + 1) * 4);
  int* curC = (int*)alloc((size_t)NCC * 4);
  int* offV = (int*)alloc((size_t)(NVV + 1) * 4);
  int* curV = (int*)alloc((size_t)NVV * 4);
  int2* cesA = (int2*)alloc((size_t)NEE * 8);  // conv A (dst=con): {edge, src}
  int2* cesB = (int2*)alloc((size_t)NEE * 8);  // conv B (dst=var)
  (void)ws_size; (void)in_sizes; (void)n_in; (void)out_size;

  unsigned short* WT[20];
  for (int i = 0; i < 20; ++i) WT[i] = WTbase + (size_t)i * 160 * KP;
  WJobs jobs;
  const float* Wsrc[20] = {cu_Wq, cu_Wk, cu_Wv, cu_We, cu_Ws,
                           vu_Wq, vu_Wk, vu_Wv, vu_We, vu_Ws,
                           eu_vW1, eu_vW2, eu_cW1, eu_cW2,
                           eu_eW1, eu_eW1 + 136 * 128, eu_eW1 + 264 * 128, eu_eW2,
                           cu_We, vu_We};
  const int Ksrc[20] = {144, 144, 144, 136, 144, 144, 144, 144, 136, 144,
                        144, 128, 144, 128, 136, 128, 128, 128, 128, 128};
  const int Tsrc[20] = {1,1,1,1,1, 1,1,1,1,1, 1,1,1,1, 1,1,1,1, 0,0};
  for (int i = 0; i < 20; ++i) {
    jobs.W[i] = Wsrc[i]; jobs.O[i] = WT[i]; jobs.K[i] = Ksrc[i]; jobs.TR[i] = Tsrc[i];
  }

  const int T = 256;
  const int NBC = (NCC + 63) / 64;    // 196
  const int NBV = (NVV + 63) / 64;    // 391
  const int NBE2 = (NEE + 127) / 128; // 1954

  // ---- pre-passes ----
  build_node_bf<<<(NVV * 40 + T - 1) / T, T, 0, stream>>>(var_learned, var_lp, var_comb_bf, NVV);
  build_node_bf<<<(NCC * 40 + T - 1) / T, T, 0, stream>>>(con_learned, con_lp, con_comb_bf, NCC);
  build_edge_bf<<<(NEE * 40 + T - 1) / T, T, 0, stream>>>(edge_learned, lo, hi, dm, wo, edge_comb_bf);
  convert_weights<<<20 * 100, T, 0, stream>>>(jobs);

  // ---- CSR builds ----
  zero2<<<(NVV + T - 1) / T, T, 0, stream>>>(countsC, NCC, countsV, NVV);
  hist2<<<(NEE + T - 1) / T, T, 0, stream>>>(eic, countsC, eiv, countsV, NEE);
  csr_scan<<<1, 256, 0, stream>>>(countsC, offC, curC, NCC);
  csr_scan<<<1, 256, 0, stream>>>(countsV, offV, curV, NVV);
  csr_scatter<<<(NEE + T - 1) / T, T, 0, stream>>>(eic, eiv, curC, cesA, NEE);
  csr_scatter<<<(NEE + T - 1) / T, T, 0, stream>>>(eiv, eic, curV, cesB, NEE);

  // ---- all independent projections in ONE dispatch ----
  {
    MBatch b{};
    b.j[0] = {con_comb_bf, WT[0], cu_bq, WT[18], bufC1, nullptr, t_bfA, NCC};  // q_c + t_c
    b.j[1] = {var_comb_bf, WT[5], vu_bq, WT[19], bufV1, nullptr, t_bfB, NVV};  // q_v + t_v
    b.j[2] = {con_comb_bf, WT[4], cu_bs, nullptr, bufC2, nullptr, nullptr, NCC}; // skip_c
    b.j[3] = {var_comb_bf, WT[9], vu_bs, nullptr, bufV2, nullptr, nullptr, NVV}; // skip_v
    b.j[4] = {var_comb_bf, WT[1], cu_bk, nullptr, nullptr, kv_bf, nullptr, NVV}; // k_v
    b.j[5] = {var_comb_bf, WT[2], cu_bv, nullptr, nullptr, vv_bf, nullptr, NVV}; // v_v
    b.start[0] = 0; b.start[1] = NBC; b.start[2] = NBC + NBV;
    b.start[3] = 2 * NBC + NBV; b.start[4] = 2 * NBC + 2 * NBV;
    b.start[5] = 2 * NBC + 3 * NBV;
    b.njobs = 6;
    gemm_multi<<<2 * NBC + 4 * NBV, 256, 0, stream>>>(b);   // 1956 blocks
  }

  // ================= Stage A: con update =================
  fused_attn<<<(NCC + 3) / 4, 256, 0, stream>>>(bufC1, kv_bf, vv_bf, t_bfA, edge_comb_bf,
                                                offC, cesA, bufC2, accE_bf, NCC);
  // con_new -> out_con; k_c,v_c; ccW chain — all from LDS-resident [con_new|lp]
  node_update<<<NBC, 256, 0, stream>>>(
      accE_bf, bufC2, con_lp, WT[3], out_con,
      WT[6], vu_bk, kv_bf, WT[7], vu_bv, vv_bf,
      WT[12], eu_cb1, WT[13], eu_cb2, WT[16], cc_bf, NCC);

  // ================= Stage B: var update =================
  fused_attn<<<(NVV + 3) / 4, 256, 0, stream>>>(bufV1, kv_bf, vv_bf, t_bfB, edge_comb_bf,
                                                offV, cesB, bufV2, accE_bf, NVV);
  // var_new -> out_var; vcW chain
  node_update<<<NBV, 256, 0, stream>>>(
      accE_bf, bufV2, var_lp, WT[8], out_var,
      nullptr, nullptr, nullptr, nullptr, nullptr, nullptr,
      WT[10], eu_vb1, WT[11], eu_vb2, WT[15], vc_bf, NVV);

  // ================= Edge stage =================
  gemm_edge2<<<NBE2, 256, 0, stream>>>(
      edge_comb_bf, WT[14], eu_eb1, vc_bf, cc_bf, eiv, eic,
      WT[17], eu_eb2, out_edge, NEE);
}